// Round 7
// baseline (591.410 us; speedup 1.0000x reference)
//
#include <hip/hip_runtime.h>

// Problem constants
constexpr int CIN   = 256;   // feature channels
constexpr int KD    = 32;    // key dim
constexpr int VD    = 128;   // value dim
constexpr int NCLS  = 10;
constexpr int BS    = 4;
constexpr int HW    = 256;   // 16*16
constexpr float BNC = 0.9999950000374997f; // 1/sqrt(1+1e-5)

typedef unsigned short u16;
typedef __attribute__((ext_vector_type(8))) __bf16 bf8v;
typedef __attribute__((ext_vector_type(4))) float f4v;

static __device__ __forceinline__ int imin(int a, int b) { return a < b ? a : b; }

static __device__ __forceinline__ u16 f2bf(float v) {
  union { float f; unsigned u; } x; x.f = v;
  unsigned r = x.u + 0x7FFFu + ((x.u >> 16) & 1u);
  return (u16)(r >> 16);
}
static __device__ __forceinline__ float bf2f(u16 h) {
  union { unsigned u; float f; } x; x.u = ((unsigned)h) << 16;
  return x.f;
}

static __device__ __forceinline__ f4v mfma16(bf8v a, bf8v b, f4v c) {
  return __builtin_amdgcn_mfma_f32_16x16x32_bf16(a, b, c, 0, 0, 0);
}

// ---------------------------------------------------------------------------
// Prep weights into MFMA-A fragment order, split bf16 hi/lo. (unchanged r6)
__global__ __launch_bounds__(256) void k_prep_w(
    const float* __restrict__ vqw, const float* __restrict__ vtw,
    const float* __restrict__ kqw, const float* __restrict__ ktw,
    u16* __restrict__ Awv, u16* __restrict__ Awk) {
  int gid = blockIdx.x * 256 + threadIdx.x;
  int lane = gid & 63;
  int grp = gid >> 6;
  const float* src; u16* dst; int kc;
  if (grp < 3456) {
    kc = grp % 72; int ot = (grp / 72) % 8; int sid = grp / (72 * 8);
    src = (sid < 5 ? vqw + (size_t)sid * VD * 2304 : vtw) + (size_t)(ot * 16 + (lane & 15)) * 2304;
    dst = Awv + (size_t)grp * 1024;
  } else {
    int g2 = grp - 3456;
    kc = g2 % 72; int ot = (g2 / 72) % 2; int sid = g2 / 144;
    src = (sid < 5 ? kqw + (size_t)sid * KD * 2304 : ktw) + (size_t)(ot * 16 + (lane & 15)) * 2304;
    dst = Awk + (size_t)g2 * 1024;
  }
  int q0 = (lane >> 4) * 8;
  int t = kc >> 3, c0 = (kc & 7) * 32;
#pragma unroll
  for (int i = 0; i < 8; ++i) {
    int c = c0 + q0 + i;
    float v = src[c * 9 + t];
    u16 h = f2bf(v);
    u16 lo = f2bf(v - bf2f(h));
    dst[lane * 8 + i] = h;
    dst[512 + lane * 8 + i] = lo;
  }
}

// ---------------------------------------------------------------------------
// Prep padded split-bf16 inputs, channel-interleaved (unchanged r6).
__global__ __launch_bounds__(256) void k_prep_x(
    const float* __restrict__ f0, const float* __restrict__ f1,
    const float* __restrict__ f2, const float* __restrict__ f3,
    const float* __restrict__ f4, const float* __restrict__ att,
    u16* __restrict__ X) {
  int img = blockIdx.x / 18, y1 = blockIdx.x % 18;
  int c = threadIdx.x;
  u16* xb = X + ((size_t)img * 18 + y1) * 18 * 512;
  const float* fin = nullptr;
  int S = 16, ylo = 0;
  float fy = 0.f;
  bool inner_y = (y1 >= 1 && y1 <= 16);
  if (img < 20 && inner_y) {
    int l = img >> 2, b = img & 3;
    S = 64 >> l;
    switch (l) {
      case 0: fin = f0; break; case 1: fin = f1; break; case 2: fin = f2; break;
      case 3: fin = f3; break; default: fin = f4; break;
    }
    fin += ((size_t)b * CIN + c) * S * S;
    int y = y1 - 1;
    float cyf = (float)(y * (S - 1)) / 15.0f;
    ylo = imin((int)cyf, S - 2); fy = cyf - (float)ylo;
  }
  for (int x1 = 0; x1 < 18; ++x1) {
    float v = 0.f;
    if (inner_y && x1 >= 1 && x1 <= 16) {
      int x = x1 - 1;
      if (img < 20) {
        float cxf = (float)(x * (S - 1)) / 15.0f;
        int xlo = imin((int)cxf, S - 2); float fx = cxf - (float)xlo;
        const float* pb = fin + ylo * S + xlo;
        float v0 = pb[0], v1 = pb[1], v2 = pb[S], v3 = pb[S + 1];
        v = (1.f - fy) * ((1.f - fx) * v0 + fx * v1) + fy * ((1.f - fx) * v2 + fx * v3);
      } else {
        v = att[(((size_t)(img - 20) * CIN + c) << 8) + (y1 - 1) * 16 + x];
      }
    }
    u16 h = f2bf(v);
    u16 lo = f2bf(v - bf2f(h));
    xb[x1 * 512 + c] = h;
    xb[x1 * 512 + 256 + c] = lo;
  }
}

// ---------------------------------------------------------------------------
// MFMA conv (unchanged r6).
__global__ __launch_bounds__(256) void k_conv_mfma(
    const u16* __restrict__ X, const u16* __restrict__ Awv, const u16* __restrict__ Awk,
    float* __restrict__ kqall, float* __restrict__ vt, float* __restrict__ f16_all,
    const float* __restrict__ vqb, const float* __restrict__ vtb,
    const float* __restrict__ kqb, const float* __restrict__ ktb) {
  int wid = blockIdx.x * 4 + (threadIdx.x >> 6);
  int lane = threadIdx.x & 63;
  bool isV = wid < 1920;
  int img, ot, yp;
  if (isV) { img = wid >> 6; int r = wid & 63; ot = r >> 3; yp = r & 7; }
  else     { int j = wid - 1920; img = j >> 4; int r = j & 15; ot = r >> 3; yp = r & 7; }
  int wset = img < 20 ? (img >> 2) : 5;

  const u16* Ab = isV ? Awv + ((size_t)(wset * 8 + ot)) * 72 * 1024
                      : Awk + ((size_t)(wset * 2 + ot)) * 72 * 1024;
  const u16* Xb = X + (size_t)img * 165888;   // 18*18*512
  int xcol = lane & 15, kg = lane >> 4;
  int y0 = yp * 2, y1 = y0 + 1;

  f4v acc0 = {0.f, 0.f, 0.f, 0.f}, acc1 = {0.f, 0.f, 0.f, 0.f};
  for (int t = 0; t < 9; ++t) {
    int dy = (t >= 6) ? 2 : (t >= 3 ? 1 : 0);
    int dx = t - dy * 3;
    const u16* Xr0 = Xb + ((size_t)((y0 + dy) * 18 + dx + xcol)) * 512 + kg * 8;
    const u16* Xr1 = Xb + ((size_t)((y1 + dy) * 18 + dx + xcol)) * 512 + kg * 8;
    const u16* Ak = Ab + (size_t)t * 8 * 1024 + lane * 8;
#pragma unroll
    for (int cc = 0; cc < 8; ++cc) {
      bf8v ah = *reinterpret_cast<const bf8v*>(Ak + cc * 1024);
      bf8v al = *reinterpret_cast<const bf8v*>(Ak + cc * 1024 + 512);
      const u16* b0 = Xr0 + cc * 32;
      const u16* b1 = Xr1 + cc * 32;
      bf8v bh0 = *reinterpret_cast<const bf8v*>(b0);
      bf8v bl0 = *reinterpret_cast<const bf8v*>(b0 + 256);
      bf8v bh1 = *reinterpret_cast<const bf8v*>(b1);
      bf8v bl1 = *reinterpret_cast<const bf8v*>(b1 + 256);
      acc0 = mfma16(ah, bh0, acc0);
      acc0 = mfma16(ah, bl0, acc0);
      acc0 = mfma16(al, bh0, acc0);
      acc1 = mfma16(ah, bh1, acc1);
      acc1 = mfma16(ah, bl1, acc1);
      acc1 = mfma16(al, bh1, acc1);
    }
  }

  float scale = 1.f;
  const float* bias;
  float* dst;
  int ocbase = ot * 16;
  if (isV) {
    if (img < 20) { dst = f16_all + ((size_t)img * CIN + ocbase) * HW; bias = vqb + wset * VD + ocbase; scale = (float)NCLS; }
    else          { dst = vt + ((size_t)(img - 20) * VD + ocbase) * HW; bias = vtb + ocbase; }
  } else {
    if (img < 20) { dst = kqall + ((size_t)img * KD + ocbase) * HW; bias = kqb + wset * KD + ocbase; }
    else          { dst = kqall + (size_t)20 * KD * HW + ((size_t)(img - 20) * KD + ocbase) * HW; bias = ktb + ocbase; }
  }
#pragma unroll
  for (int i = 0; i < 4; ++i) {
    int ocl = kg * 4 + i;
    float bv = bias[ocl];
    dst[(size_t)ocl * HW + y0 * 16 + xcol] = (acc0[i] + bv) * scale;
    dst[(size_t)ocl * HW + y1 * 16 + xcol] = (acc1[i] + bv) * scale;
  }
}

// ---------------------------------------------------------------------------
// vt (f32) -> split bf16 [2][10][128][256]. grid = 320.
__global__ __launch_bounds__(256) void k_prep_vt(
    const float* __restrict__ vt, u16* __restrict__ vt2) {
  int gid = blockIdx.x * 256 + threadIdx.x;   // * 4 elems
  float4 v = *reinterpret_cast<const float4*>(vt + (size_t)gid * 4);
  const float* vv = (const float*)&v;
  u16 h[4], l[4];
#pragma unroll
  for (int e = 0; e < 4; ++e) { h[e] = f2bf(vv[e]); l[e] = f2bf(vv[e] - bf2f(h[e])); }
  uint2 wh, wl;
  wh.x = (unsigned)h[0] | ((unsigned)h[1] << 16); wh.y = (unsigned)h[2] | ((unsigned)h[3] << 16);
  wl.x = (unsigned)l[0] | ((unsigned)l[1] << 16); wl.y = (unsigned)l[2] | ((unsigned)l[3] << 16);
  *reinterpret_cast<uint2*>(vt2 + (size_t)gid * 4) = wh;
  *reinterpret_cast<uint2*>(vt2 + 327680 + (size_t)gid * 4) = wl;
}

// cw first-256 columns -> split bf16 [2][256oc][256c]. grid = 64.
__global__ __launch_bounds__(256) void k_prep_cw(
    const float* __restrict__ cw, u16* __restrict__ cwA) {
  int gid = blockIdx.x * 256 + threadIdx.x;   // 16384, * 4 c
  int oc = gid >> 6, c0 = (gid & 63) * 4;
  float4 v = *reinterpret_cast<const float4*>(cw + (size_t)oc * 512 + c0);
  const float* vv = (const float*)&v;
  u16 h[4], l[4];
#pragma unroll
  for (int e = 0; e < 4; ++e) { h[e] = f2bf(vv[e]); l[e] = f2bf(vv[e] - bf2f(h[e])); }
  uint2 wh, wl;
  wh.x = (unsigned)h[0] | ((unsigned)h[1] << 16); wh.y = (unsigned)h[2] | ((unsigned)h[3] << 16);
  wl.x = (unsigned)l[0] | ((unsigned)l[1] << 16); wl.y = (unsigned)l[2] | ((unsigned)l[3] << 16);
  *reinterpret_cast<uint2*>(cwA + (size_t)oc * 256 + c0) = wh;
  *reinterpret_cast<uint2*>(cwA + 65536 + (size_t)oc * 256 + c0) = wl;
}

// ---------------------------------------------------------------------------
// feats -> transposed split-bf16 Xf[gpx][2][256]. grid = 344 (see mapping).
__global__ __launch_bounds__(256) void k_prep_f(
    const float* __restrict__ f0, const float* __restrict__ f1,
    const float* __restrict__ f2, const float* __restrict__ f3,
    const float* __restrict__ f4, u16* __restrict__ Xf) {
  int blk = blockIdx.x;
  int l, base, nb;
  if (blk < 256)      { l = 0; base = 0;   nb = 64; }
  else if (blk < 320) { l = 1; base = 256; nb = 16; }
  else if (blk < 336) { l = 2; base = 320; nb = 4; }
  else if (blk < 340) { l = 3; base = 336; nb = 1; }
  else                { l = 4; base = 340; nb = 1; }
  int local = blk - base;
  int b = local / nb, chunk = local % nb;
  int S = 64 >> l, SS = S * S;
  int px0 = chunk * 64;
  const float* fin = (l == 0 ? f0 : l == 1 ? f1 : l == 2 ? f2 : l == 3 ? f3 : f4)
                     + (size_t)b * CIN * SS;
  const int jbase[5] = {0, 16384, 20480, 21504, 21760};
  int gpx0 = jbase[l] + b * SS + px0;
  int tid = threadIdx.x;
  __shared__ float sm[16][65];
  int px_r = tid & 63, cr = tid >> 6;
  int px_w = tid >> 2, c4 = (tid & 3) * 4;
  for (int cb = 0; cb < 16; ++cb) {
    __syncthreads();
#pragma unroll
    for (int q = 0; q < 4; ++q) {
      int cl = q * 4 + cr;
      float v = 0.f;
      if (px0 + px_r < SS) v = fin[(size_t)(cb * 16 + cl) * SS + px0 + px_r];
      sm[cl][px_r] = v;
    }
    __syncthreads();
    if (px0 + px_w < SS) {
      u16 hh[4], ll[4];
#pragma unroll
      for (int e = 0; e < 4; ++e) {
        float v = sm[c4 + e][px_w];
        hh[e] = f2bf(v); ll[e] = f2bf(v - bf2f(hh[e]));
      }
      uint2 wh, wl;
      wh.x = (unsigned)hh[0] | ((unsigned)hh[1] << 16); wh.y = (unsigned)hh[2] | ((unsigned)hh[3] << 16);
      wl.x = (unsigned)ll[0] | ((unsigned)ll[1] << 16); wl.y = (unsigned)ll[2] | ((unsigned)ll[3] << 16);
      u16* dst = Xf + (size_t)(gpx0 + px_w) * 512 + cb * 16 + c4;
      *reinterpret_cast<uint2*>(dst) = wh;
      *reinterpret_cast<uint2*>(dst + 256) = wl;
    }
  }
}

// ---------------------------------------------------------------------------
// Fused p: scores + softmax(over i); writes pT[bn][j][i] as split bf16.
// grid = 40*8 (bn, jt of 32 j); block = 256 = 8 iq-groups x 32 jl.
__global__ __launch_bounds__(256) void k_p_fused(
    const float* __restrict__ kq_lvl, const float* __restrict__ ktb,
    u16* __restrict__ pTh, u16* __restrict__ pTl) {
  int bn = blockIdx.x >> 3, jt = blockIdx.x & 7;
  int b = bn / NCLS, n = bn % NCLS;
  int t = threadIdx.x;
  int iq = t >> 5, jl = t & 31;
  int j = jt * 32 + jl;

  __shared__ float kqs[KD][HW];
  float ktr[KD];
#pragma unroll
  for (int k = 0; k < KD; ++k) ktr[k] = ktb[((size_t)n * KD + k) * HW + j];
  const float* kqb = kq_lvl + (size_t)b * KD * HW;
  for (int s = t; s < KD * HW; s += 256) ((float*)kqs)[s] = kqb[s];
  __syncthreads();

  float v[32];
#pragma unroll
  for (int ii = 0; ii < 32; ++ii) v[ii] = 0.f;
  for (int k = 0; k < KD; ++k) {
    float a = ktr[k];
    const float4* q4 = (const float4*)&kqs[k][iq * 32];
#pragma unroll
    for (int q = 0; q < 8; ++q) {
      float4 u = q4[q];
      v[q * 4 + 0] += u.x * a; v[q * 4 + 1] += u.y * a;
      v[q * 4 + 2] += u.z * a; v[q * 4 + 3] += u.w * a;
    }
  }
  float ml = -1e30f;
#pragma unroll
  for (int ii = 0; ii < 32; ++ii) ml = fmaxf(ml, v[ii]);
  float sl = 0.f;
#pragma unroll
  for (int ii = 0; ii < 32; ++ii) sl += __expf(v[ii] - ml);

  __syncthreads();
  float* red = (float*)kqs;
  red[iq * 32 + jl] = ml;
  red[256 + iq * 32 + jl] = sl;
  __syncthreads();
  float M = -1e30f;
#pragma unroll
  for (int q = 0; q < 8; ++q) M = fmaxf(M, red[q * 32 + jl]);
  float S = 0.f;
#pragma unroll
  for (int q = 0; q < 8; ++q) S += red[256 + q * 32 + jl] * __expf(red[q * 32 + jl] - M);
  float inv = 1.0f / S;

  size_t pbase = ((size_t)bn * HW + j) * HW + iq * 32;
  u16* ph = pTh + pbase;
  u16* pl = pTl + pbase;
#pragma unroll
  for (int q = 0; q < 4; ++q) {
    unsigned hw[4], lw[4];
#pragma unroll
    for (int w = 0; w < 4; ++w) {
      float p0 = __expf(v[q * 8 + w * 2] - M) * inv;
      float p1 = __expf(v[q * 8 + w * 2 + 1] - M) * inv;
      u16 h0 = f2bf(p0); u16 l0 = f2bf(p0 - bf2f(h0));
      u16 h1 = f2bf(p1); u16 l1 = f2bf(p1 - bf2f(h1));
      hw[w] = (unsigned)h0 | ((unsigned)h1 << 16);
      lw[w] = (unsigned)l0 | ((unsigned)l1 << 16);
    }
    reinterpret_cast<uint4*>(ph)[q] = make_uint4(hw[0], hw[1], hw[2], hw[3]);
    reinterpret_cast<uint4*>(pl)[q] = make_uint4(lw[0], lw[1], lw[2], lw[3]);
  }
}

// ---------------------------------------------------------------------------
// fa from pT: block = (bn, jg of 16 j). Stage [16 j][256 i] (reconstructed
// fp32), emit 16*S*S pixels with coalesced float4 stores.
__global__ __launch_bounds__(256) void k_fa_t(
    const u16* __restrict__ pTh, const u16* __restrict__ pTl,
    float* __restrict__ out, int S, int shift) {
  int bn = blockIdx.x >> 4, jg = blockIdx.x & 15;
  int tid = threadIdx.x;
  __shared__ float ld[16][257];
  {
    int jj = tid >> 4, ii0 = (tid & 15) * 16;
    size_t base = ((size_t)bn * HW + jg * 16 + jj) * HW + ii0;
    const uint4* ph = reinterpret_cast<const uint4*>(pTh + base);
    const uint4* pl = reinterpret_cast<const uint4*>(pTl + base);
#pragma unroll
    for (int q = 0; q < 2; ++q) {
      uint4 H = ph[q], L = pl[q];
      const unsigned* hu = (const unsigned*)&H;
      const unsigned* lu = (const unsigned*)&L;
#pragma unroll
      for (int w = 0; w < 4; ++w) {
        ld[jj][ii0 + q * 8 + w * 2]     = bf2f((u16)(hu[w] & 0xffff)) + bf2f((u16)(lu[w] & 0xffff));
        ld[jj][ii0 + q * 8 + w * 2 + 1] = bf2f((u16)(hu[w] >> 16))    + bf2f((u16)(lu[w] >> 16));
      }
    }
  }
  __syncthreads();

  int SS = S * S, tot = SS << 4;
  for (int base = tid * 4; base < tot; base += 1024) {
    int jj = base >> (2 * shift);
    int rest = base & (SS - 1);
    int X0 = rest & (S - 1), Y = rest >> shift;
    float cyf = (float)(Y * 15) / (float)(S - 1);
    int ylo = imin((int)cyf, 14); float fy = cyf - (float)ylo;
    float4 r; float* rr = (float*)&r;
#pragma unroll
    for (int t4 = 0; t4 < 4; ++t4) {
      int X = X0 + t4;
      float cxf = (float)(X * 15) / (float)(S - 1);
      int xlo = imin((int)cxf, 14); float fx = cxf - (float)xlo;
      int i00 = ylo * 16 + xlo;
      float v0 = ld[jj][i00],      v1 = ld[jj][i00 + 1];
      float v2 = ld[jj][i00 + 16], v3 = ld[jj][i00 + 17];
      rr[t4] = (1.f - fy) * ((1.f - fx) * v0 + fx * v1)
             + fy * ((1.f - fx) * v2 + fx * v3);
    }
    *(float4*)(out + ((size_t)bn * HW + jg * 16 + jj) * SS + rest) = r;
  }
}

// ---------------------------------------------------------------------------
// MFMA agg: aggn[bn,c,j] = sum_i vt[n,c,i]*p[bn,i,j]. A = vt2 (split bf16),
// B = pT (split bf16). wave = (bn, ctile of 16 c, jq of 64 j). grid = 320x256.
__global__ __launch_bounds__(256) void k_aggn_mfma(
    const u16* __restrict__ vt2, const u16* __restrict__ pTh,
    const u16* __restrict__ pTl, float* __restrict__ aggn) {
  int wid = blockIdx.x * 4 + (threadIdx.x >> 6);   // 0..1279
  int lane = threadIdx.x & 63;
  int bn = wid >> 5; int r = wid & 31;
  int ctile = r >> 2, jq = r & 3;
  int n = bn % NCLS;
  int row = lane & 15, kg = lane >> 4;
  const u16* vh = vt2 + ((size_t)n * VD + ctile * 16 + row) * 256 + kg * 8;
  const u16* vl = vh + 327680;
  f4v acc[4] = {{0.f,0.f,0.f,0.f},{0.f,0.f,0.f,0.f},{0.f,0.f,0.f,0.f},{0.f,0.f,0.f,0.f}};
  for (int kc = 0; kc < 8; ++kc) {
    bf8v ah = *reinterpret_cast<const bf8v*>(vh + kc * 32);
    bf8v al = *reinterpret_cast<const bf8v*>(vl + kc * 32);
#pragma unroll
    for (int q = 0; q < 4; ++q) {
      int j = jq * 64 + q * 16 + row;
      size_t ba = ((size_t)bn * HW + j) * HW + kc * 32 + kg * 8;
      bf8v bh = *reinterpret_cast<const bf8v*>(pTh + ba);
      bf8v bl = *reinterpret_cast<const bf8v*>(pTl + ba);
      acc[q] = mfma16(ah, bh, acc[q]);
      acc[q] = mfma16(ah, bl, acc[q]);
      acc[q] = mfma16(al, bh, acc[q]);
    }
  }
#pragma unroll
  for (int q = 0; q < 4; ++q)
#pragma unroll
    for (int i = 0; i < 4; ++i)
      aggn[((size_t)bn * VD + ctile * 16 + kg * 4 + i) * HW + jq * 64 + q * 16 + row] = acc[q][i];
}

// f16[b, 128+c, j] = sum_n aggn[b,n,c,j].  total = BS*VD*HW = 131072
__global__ __launch_bounds__(256) void k_aggred(
    const float* __restrict__ aggn, float* __restrict__ f16) {
  int idx = blockIdx.x * 256 + threadIdx.x;
  int j = idx & 255;
  int c = (idx >> 8) & 127;
  int b = idx >> 15;
  float s = 0.f;
#pragma unroll
  for (int n = 0; n < NCLS; ++n)
    s += aggn[(((size_t)b * NCLS + n) * VD + c) * HW + j];
  f16[((size_t)b * CIN + VD + c) * HW + j] = s;
}

// ---------------------------------------------------------------------------
// g16_all[l,b,oc,j] = sum_c cw[oc,256+c]*(gamma[l,c]*BNC)*f16_all[l,b,c,j]
__global__ __launch_bounds__(256) void k_g16_all(
    const float* __restrict__ f16_all, const float* __restrict__ cw,
    const float* __restrict__ gamma, float* __restrict__ g16_all) {
  int blk = blockIdx.x;
  int l = blk >> 7, b = (blk >> 5) & 3, ocg = blk & 31;
  int j = threadIdx.x;
  const float* f16 = f16_all + (size_t)(l * 4 + b) * CIN * HW;
  const float* gm  = gamma + l * CIN;
  float acc[8] = {};
  for (int c = 0; c < CIN; ++c) {
    float fv = f16[(size_t)c * HW + j] * (gm[c] * BNC);
#pragma unroll
    for (int o = 0; o < 8; ++o)
      acc[o] += cw[(size_t)(ocg * 8 + o) * 512 + 256 + c] * fv;
  }
  for (int o = 0; o < 8; ++o)
    g16_all[((size_t)(l * 4 + b) * CIN + ocg * 8 + o) * HW + j] = acc[o];
}

// cb[l,oc] = combine_b[oc] + sum_c cw[oc,256+c]*beta[l,c].  grid=5, block=256
__global__ __launch_bounds__(256) void k_cb(
    const float* __restrict__ cw, const float* __restrict__ cbias,
    const float* __restrict__ beta, float* __restrict__ cb) {
  int l = blockIdx.x, oc = threadIdx.x;
  float s = cbias[oc];
  for (int c = 0; c < CIN; ++c)
    s += cw[(size_t)oc * 512 + 256 + c] * beta[l * CIN + c];
  cb[l * CIN + oc] = s;
}

// ---------------------------------------------------------------------------
// Resize g16 (+cb) into out (base term). block = (img, ocg of 16). grid=320.
__global__ __launch_bounds__(256) void k_rg(
    const float* __restrict__ g16_all, const float* __restrict__ cb_all,
    float* __restrict__ out) {
  int img = blockIdx.x >> 4, ocg = blockIdx.x & 15;
  int l = img >> 2, b = img & 3;
  int tid = threadIdx.x;
  __shared__ float ld[16][257];
  const float* gb = g16_all + ((size_t)img * CIN + ocg * 16) * HW;
  for (int t2 = tid; t2 < 4096; t2 += 256)
    ld[t2 >> 8][t2 & 255] = gb[t2];
  __syncthreads();
  int S = 64 >> l, shift = 6 - l, SS = S * S;
  const size_t ooff[5] = {0, 4194304, 5242880, 5505024, 5570560};
  float* ob = out + ooff[l] + ((size_t)b * CIN + ocg * 16) * SS;
  int tot = SS << 4;
  for (int basei = tid * 4; basei < tot; basei += 1024) {
    int oc = basei >> (2 * shift);
    int rest = basei & (SS - 1);
    int X0 = rest & (S - 1), Y = rest >> shift;
    float cyf = (float)(Y * 15) / (float)(S - 1);
    int ylo = imin((int)cyf, 14); float fy = cyf - (float)ylo;
    float cbs = cb_all[l * CIN + ocg * 16 + oc];
    float4 rv; float* rr = (float*)&rv;
#pragma unroll
    for (int t4 = 0; t4 < 4; ++t4) {
      int X = X0 + t4;
      float cxf = (float)(X * 15) / (float)(S - 1);
      int xlo = imin((int)cxf, 14); float fx = cxf - (float)xlo;
      int i00 = ylo * 16 + xlo;
      float v0 = ld[oc][i00],      v1 = ld[oc][i00 + 1];
      float v2 = ld[oc][i00 + 16], v3 = ld[oc][i00 + 17];
      rr[t4] = (1.f - fy) * ((1.f - fx) * v0 + fx * v1)
             + fy * ((1.f - fx) * v2 + fx * v3) + cbs;
    }
    *(float4*)(ob + (size_t)oc * SS + rest) = rv;
  }
}

// ---------------------------------------------------------------------------
// out += cw[:, :256] . f  (MFMA GEMM over all level images).
// wave = (pxtile pt, octile). grid = 5456 x 256 (21824 waves).
__global__ __launch_bounds__(256) void k_out_mfma(
    const u16* __restrict__ cwA, const u16* __restrict__ Xf,
    float* __restrict__ out) {
  int wid = blockIdx.x * 4 + (threadIdx.x >> 6);
  int lane = threadIdx.x & 63;
  int pt = wid >> 4, octile = wid & 15;
  int l, lb, tl;
  if (pt < 1024)      { l = 0; lb = 0;    tl = 256; }
  else if (pt < 1280) { l = 1; lb = 1024; tl = 64; }
  else if (pt < 1344) { l = 2; lb = 1280; tl = 16; }
  else if (pt < 1360) { l = 3; lb = 1344; tl = 4; }
  else                { l = 4; lb = 1360; tl = 1; }
  int rem = pt - lb;
  int b = rem / tl;
  int pxin = (rem % tl) * 16;
  const int jbase[5] = {0, 16384, 20480, 21504, 21760};
  const size_t ooff[5] = {0, 4194304, 5242880, 5505024, 5570560};
  int S = 64 >> l, SS = S * S;
  int row = lane & 15, kg = lane >> 4;
  int gpx = jbase[l] + b * SS + pxin + row;

  const u16* Ah = cwA + ((size_t)(octile * 16 + row)) * 256 + kg * 8;
  const u16* Al = Ah + 65536;
  const u16* Bh = Xf + (size_t)gpx * 512 + kg * 8;
  const u16* Bl = Bh + 256;
  f4v acc = {0.f, 0.f, 0.f, 0.f};
#pragma unroll
  for (int kc = 0; kc < 8; ++kc) {
    bf8v ah = *reinterpret_cast<const bf8v*>(Ah + kc * 32);
    bf8v al = *reinterpret_cast<const bf8v*>(Al + kc * 32);
    bf8v bh = *reinterpret_cast<const bf8v*>(Bh + kc * 32);
    bf8v bl = *reinterpret_cast<const bf8v*>(Bl + kc * 32);
    acc = mfma16(ah, bh, acc);
    acc = mfma16(ah, bl, acc);
    acc = mfma16(al, bh, acc);
  }
  float* ob = out + ooff[l] + ((size_t)b * CIN + octile * 16) * SS + pxin + row;
#pragma unroll
  for (int i = 0; i < 4; ++i) {
    float* po = ob + (size_t)(kg * 4 + i) * SS;
    *po += acc[i];
  }
}

// ===========================================================================
extern "C" void kernel_launch(void* const* d_in, const int* in_sizes, int n_in,
                              void* d_out, int out_size, void* d_ws, size_t ws_size,
                              hipStream_t stream) {
  const float* feat[5];
  for (int l = 0; l < 5; ++l) feat[l] = (const float*)d_in[l];
  const float* att   = (const float*)d_in[5];
  const float* ktw   = (const float*)d_in[6];
  const float* ktb   = (const float*)d_in[7];
  const float* vtw   = (const float*)d_in[8];
  const float* vtb   = (const float*)d_in[9];
  const float* kqw   = (const float*)d_in[10];
  const float* kqb   = (const float*)d_in[11];
  const float* vqw   = (const float*)d_in[12];
  const float* vqb   = (const float*)d_in[13];
  const float* gamma = (const float*)d_in[14];
  const float* beta  = (const float*)d_in[15];
  const float* cw    = (const float*)d_in[16];
  const float* cbias = (const float*)d_in[17];
  float* out = (float*)d_out;

  // workspace layout (floats), total 12,565,760 fl = 50.3 MB
  float* ws      = (float*)d_ws;
  float* kqall   = ws;                     // [30][32][256]   245760
  float* vt      = ws + 245760;            // [10][128][256]  327680
  float* f16_all = ws + 573440;            // [20][256][256]  1310720
  u16*   vt2     = (u16*)(ws + 1884160);   // [2][10][128][256] u16 = 327680 fl
  u16*   cwA     = (u16*)(ws + 2211840);   // [2][256][256] u16     = 65536 fl
  float* cb      = ws + 2277376;           // [5][256]              = 1280
  u16*   Xf      = (u16*)(ws + 2278656);   // [21824][2][256] u16   = 5586944 fl
  float* Sreg    = ws + 7865600;           // shared region, 4700160 fl
  // phase 1 (conv):  X | Awv | Awk
  u16*   X       = (u16*)Sreg;                 // 30*18*18*512 u16 = 2488320 fl
  u16*   Awv     = (u16*)(Sreg + 2488320);     // 3538944 u16 = 1769472 fl
  u16*   Awk     = (u16*)(Sreg + 4257792);     //  884736 u16 = 442368 fl
  // phase 2 (p-chain): pTh | pTl | aggn
  u16*   pTh     = (u16*)Sreg;                 // 2621440 u16 = 1310720 fl
  u16*   pTl     = pTh + 2621440;              // 2621440 u16 = 1310720 fl
  float* aggn    = Sreg + 2621440;             // 1310720 fl
  // phase 3: g16_all
  float* g16_all = Sreg;                       // 1310720 fl

  size_t fa_off[5];
  {
    size_t off = 5586944;
    static const int szs[5] = {64, 32, 16, 8, 4};
    for (int l = 0; l < 5; ++l) { fa_off[l] = off; off += (size_t)BS * NCLS * HW * szs[l] * szs[l]; }
  }
  static const int sizes[5]  = {64, 32, 16, 8, 4};
  static const int shifts[5] = {6, 5, 4, 3, 2};

  // Phase 1: preps + MFMA convs
  k_prep_x<<<540, 256, 0, stream>>>(
      feat[0], feat[1], feat[2], feat[3], feat[4], att, X);
  k_prep_w<<<1080, 256, 0, stream>>>(vqw, vtw, kqw, ktw, Awv, Awk);
  k_prep_f<<<344, 256, 0, stream>>>(
      feat[0], feat[1], feat[2], feat[3], feat[4], Xf);
  k_prep_cw<<<64, 256, 0, stream>>>(cw, cwA);
  k_cb<<<5, 256, 0, stream>>>(cw, cbias, beta, cb);
  k_conv_mfma<<<600, 256, 0, stream>>>(
      X, Awv, Awk, kqall, vt, f16_all, vqb, vtb, kqb, ktb);
  k_prep_vt<<<320, 256, 0, stream>>>(vt, vt2);

  // Phase 2: per-level p-chain
  for (int l = 0; l < 5; ++l) {
    k_p_fused<<<40 * 8, 256, 0, stream>>>(
        kqall + (size_t)l * 4 * KD * HW, kqall + 20 * KD * HW, pTh, pTl);
    k_fa_t<<<40 * 16, 256, 0, stream>>>(pTh, pTl, out + fa_off[l], sizes[l], shifts[l]);
    k_aggn_mfma<<<320, 256, 0, stream>>>(vt2, pTh, pTl, aggn);
    k_aggred<<<BS * VD * HW / 256, 256, 0, stream>>>(
        aggn, f16_all + (size_t)l * 4 * CIN * HW);
  }

  // Phase 3: combine
  k_g16_all<<<5 * 4 * 32, 256, 0, stream>>>(f16_all, cw, gamma, g16_all);
  k_rg<<<320, 256, 0, stream>>>(g16_all, cb, out);
  k_out_mfma<<<5456, 256, 0, stream>>>(cwA, Xf, out);
}

// Round 8
// 410.138 us; speedup vs baseline: 1.4420x; 1.4420x over previous
//
#include <hip/hip_runtime.h>

// Problem constants
constexpr int CIN   = 256;   // feature channels
constexpr int KD    = 32;    // key dim
constexpr int VD    = 128;   // value dim
constexpr int NCLS  = 10;
constexpr int BS    = 4;
constexpr int HW    = 256;   // 16*16
constexpr float BNC = 0.9999950000374997f; // 1/sqrt(1+1e-5)

typedef unsigned short u16;
typedef __attribute__((ext_vector_type(8))) __bf16 bf8v;
typedef __attribute__((ext_vector_type(4))) float f4v;

static __device__ __forceinline__ int imin(int a, int b) { return a < b ? a : b; }

static __device__ __forceinline__ u16 f2bf(float v) {
  union { float f; unsigned u; } x; x.f = v;
  unsigned r = x.u + 0x7FFFu + ((x.u >> 16) & 1u);
  return (u16)(r >> 16);
}
static __device__ __forceinline__ float bf2f(u16 h) {
  union { unsigned u; float f; } x; x.u = ((unsigned)h) << 16;
  return x.f;
}

static __device__ __forceinline__ f4v mfma16(bf8v a, bf8v b, f4v c) {
  return __builtin_amdgcn_mfma_f32_16x16x32_bf16(a, b, c, 0, 0, 0);
}

// ---------------------------------------------------------------------------
// Prep weights into MFMA-A fragment order, split bf16 hi/lo. (unchanged)
__global__ __launch_bounds__(256) void k_prep_w(
    const float* __restrict__ vqw, const float* __restrict__ vtw,
    const float* __restrict__ kqw, const float* __restrict__ ktw,
    u16* __restrict__ Awv, u16* __restrict__ Awk) {
  int gid = blockIdx.x * 256 + threadIdx.x;
  int lane = gid & 63;
  int grp = gid >> 6;
  const float* src; u16* dst; int kc;
  if (grp < 3456) {
    kc = grp % 72; int ot = (grp / 72) % 8; int sid = grp / (72 * 8);
    src = (sid < 5 ? vqw + (size_t)sid * VD * 2304 : vtw) + (size_t)(ot * 16 + (lane & 15)) * 2304;
    dst = Awv + (size_t)grp * 1024;
  } else {
    int g2 = grp - 3456;
    kc = g2 % 72; int ot = (g2 / 72) % 2; int sid = g2 / 144;
    src = (sid < 5 ? kqw + (size_t)sid * KD * 2304 : ktw) + (size_t)(ot * 16 + (lane & 15)) * 2304;
    dst = Awk + (size_t)g2 * 1024;
  }
  int q0 = (lane >> 4) * 8;
  int t = kc >> 3, c0 = (kc & 7) * 32;
#pragma unroll
  for (int i = 0; i < 8; ++i) {
    int c = c0 + q0 + i;
    float v = src[c * 9 + t];
    u16 h = f2bf(v);
    u16 lo = f2bf(v - bf2f(h));
    dst[lane * 8 + i] = h;
    dst[512 + lane * 8 + i] = lo;
  }
}

// ---------------------------------------------------------------------------
// Prep padded split-bf16 inputs, channel-interleaved (unchanged).
__global__ __launch_bounds__(256) void k_prep_x(
    const float* __restrict__ f0, const float* __restrict__ f1,
    const float* __restrict__ f2, const float* __restrict__ f3,
    const float* __restrict__ f4, const float* __restrict__ att,
    u16* __restrict__ X) {
  int img = blockIdx.x / 18, y1 = blockIdx.x % 18;
  int c = threadIdx.x;
  u16* xb = X + ((size_t)img * 18 + y1) * 18 * 512;
  const float* fin = nullptr;
  int S = 16, ylo = 0;
  float fy = 0.f;
  bool inner_y = (y1 >= 1 && y1 <= 16);
  if (img < 20 && inner_y) {
    int l = img >> 2, b = img & 3;
    S = 64 >> l;
    switch (l) {
      case 0: fin = f0; break; case 1: fin = f1; break; case 2: fin = f2; break;
      case 3: fin = f3; break; default: fin = f4; break;
    }
    fin += ((size_t)b * CIN + c) * S * S;
    int y = y1 - 1;
    float cyf = (float)(y * (S - 1)) / 15.0f;
    ylo = imin((int)cyf, S - 2); fy = cyf - (float)ylo;
  }
  for (int x1 = 0; x1 < 18; ++x1) {
    float v = 0.f;
    if (inner_y && x1 >= 1 && x1 <= 16) {
      int x = x1 - 1;
      if (img < 20) {
        float cxf = (float)(x * (S - 1)) / 15.0f;
        int xlo = imin((int)cxf, S - 2); float fx = cxf - (float)xlo;
        const float* pb = fin + ylo * S + xlo;
        float v0 = pb[0], v1 = pb[1], v2 = pb[S], v3 = pb[S + 1];
        v = (1.f - fy) * ((1.f - fx) * v0 + fx * v1) + fy * ((1.f - fx) * v2 + fx * v3);
      } else {
        v = att[(((size_t)(img - 20) * CIN + c) << 8) + (y1 - 1) * 16 + x];
      }
    }
    u16 h = f2bf(v);
    u16 lo = f2bf(v - bf2f(h));
    xb[x1 * 512 + c] = h;
    xb[x1 * 512 + 256 + c] = lo;
  }
}

// ---------------------------------------------------------------------------
// MFMA conv (unchanged).
__global__ __launch_bounds__(256) void k_conv_mfma(
    const u16* __restrict__ X, const u16* __restrict__ Awv, const u16* __restrict__ Awk,
    float* __restrict__ kqall, float* __restrict__ vt, float* __restrict__ f16_all,
    const float* __restrict__ vqb, const float* __restrict__ vtb,
    const float* __restrict__ kqb, const float* __restrict__ ktb) {
  int wid = blockIdx.x * 4 + (threadIdx.x >> 6);
  int lane = threadIdx.x & 63;
  bool isV = wid < 1920;
  int img, ot, yp;
  if (isV) { img = wid >> 6; int r = wid & 63; ot = r >> 3; yp = r & 7; }
  else     { int j = wid - 1920; img = j >> 4; int r = j & 15; ot = r >> 3; yp = r & 7; }
  int wset = img < 20 ? (img >> 2) : 5;

  const u16* Ab = isV ? Awv + ((size_t)(wset * 8 + ot)) * 72 * 1024
                      : Awk + ((size_t)(wset * 2 + ot)) * 72 * 1024;
  const u16* Xb = X + (size_t)img * 165888;   // 18*18*512
  int xcol = lane & 15, kg = lane >> 4;
  int y0 = yp * 2, y1 = y0 + 1;

  f4v acc0 = {0.f, 0.f, 0.f, 0.f}, acc1 = {0.f, 0.f, 0.f, 0.f};
  for (int t = 0; t < 9; ++t) {
    int dy = (t >= 6) ? 2 : (t >= 3 ? 1 : 0);
    int dx = t - dy * 3;
    const u16* Xr0 = Xb + ((size_t)((y0 + dy) * 18 + dx + xcol)) * 512 + kg * 8;
    const u16* Xr1 = Xb + ((size_t)((y1 + dy) * 18 + dx + xcol)) * 512 + kg * 8;
    const u16* Ak = Ab + (size_t)t * 8 * 1024 + lane * 8;
#pragma unroll
    for (int cc = 0; cc < 8; ++cc) {
      bf8v ah = *reinterpret_cast<const bf8v*>(Ak + cc * 1024);
      bf8v al = *reinterpret_cast<const bf8v*>(Ak + cc * 1024 + 512);
      const u16* b0 = Xr0 + cc * 32;
      const u16* b1 = Xr1 + cc * 32;
      bf8v bh0 = *reinterpret_cast<const bf8v*>(b0);
      bf8v bl0 = *reinterpret_cast<const bf8v*>(b0 + 256);
      bf8v bh1 = *reinterpret_cast<const bf8v*>(b1);
      bf8v bl1 = *reinterpret_cast<const bf8v*>(b1 + 256);
      acc0 = mfma16(ah, bh0, acc0);
      acc0 = mfma16(ah, bl0, acc0);
      acc0 = mfma16(al, bh0, acc0);
      acc1 = mfma16(ah, bh1, acc1);
      acc1 = mfma16(ah, bl1, acc1);
      acc1 = mfma16(al, bh1, acc1);
    }
  }

  float scale = 1.f;
  const float* bias;
  float* dst;
  int ocbase = ot * 16;
  if (isV) {
    if (img < 20) { dst = f16_all + ((size_t)img * CIN + ocbase) * HW; bias = vqb + wset * VD + ocbase; scale = (float)NCLS; }
    else          { dst = vt + ((size_t)(img - 20) * VD + ocbase) * HW; bias = vtb + ocbase; }
  } else {
    if (img < 20) { dst = kqall + ((size_t)img * KD + ocbase) * HW; bias = kqb + wset * KD + ocbase; }
    else          { dst = kqall + (size_t)20 * KD * HW + ((size_t)(img - 20) * KD + ocbase) * HW; bias = ktb + ocbase; }
  }
#pragma unroll
  for (int i = 0; i < 4; ++i) {
    int ocl = kg * 4 + i;
    float bv = bias[ocl];
    dst[(size_t)ocl * HW + y0 * 16 + xcol] = (acc0[i] + bv) * scale;
    dst[(size_t)ocl * HW + y1 * 16 + xcol] = (acc1[i] + bv) * scale;
  }
}

// ---------------------------------------------------------------------------
// vt (f32) -> split bf16 [2][10][128][256]. grid = 320. (unchanged)
__global__ __launch_bounds__(256) void k_prep_vt(
    const float* __restrict__ vt, u16* __restrict__ vt2) {
  int gid = blockIdx.x * 256 + threadIdx.x;   // * 4 elems
  float4 v = *reinterpret_cast<const float4*>(vt + (size_t)gid * 4);
  const float* vv = (const float*)&v;
  u16 h[4], l[4];
#pragma unroll
  for (int e = 0; e < 4; ++e) { h[e] = f2bf(vv[e]); l[e] = f2bf(vv[e] - bf2f(h[e])); }
  uint2 wh, wl;
  wh.x = (unsigned)h[0] | ((unsigned)h[1] << 16); wh.y = (unsigned)h[2] | ((unsigned)h[3] << 16);
  wl.x = (unsigned)l[0] | ((unsigned)l[1] << 16); wl.y = (unsigned)l[2] | ((unsigned)l[3] << 16);
  *reinterpret_cast<uint2*>(vt2 + (size_t)gid * 4) = wh;
  *reinterpret_cast<uint2*>(vt2 + 327680 + (size_t)gid * 4) = wl;
}

// cw first-256 columns -> split bf16 [2][256oc][256c]. grid = 64. (unchanged)
__global__ __launch_bounds__(256) void k_prep_cw(
    const float* __restrict__ cw, u16* __restrict__ cwA) {
  int gid = blockIdx.x * 256 + threadIdx.x;   // 16384, * 4 c
  int oc = gid >> 6, c0 = (gid & 63) * 4;
  float4 v = *reinterpret_cast<const float4*>(cw + (size_t)oc * 512 + c0);
  const float* vv = (const float*)&v;
  u16 h[4], l[4];
#pragma unroll
  for (int e = 0; e < 4; ++e) { h[e] = f2bf(vv[e]); l[e] = f2bf(vv[e] - bf2f(h[e])); }
  uint2 wh, wl;
  wh.x = (unsigned)h[0] | ((unsigned)h[1] << 16); wh.y = (unsigned)h[2] | ((unsigned)h[3] << 16);
  wl.x = (unsigned)l[0] | ((unsigned)l[1] << 16); wl.y = (unsigned)l[2] | ((unsigned)l[3] << 16);
  *reinterpret_cast<uint2*>(cwA + (size_t)oc * 256 + c0) = wh;
  *reinterpret_cast<uint2*>(cwA + 65536 + (size_t)oc * 256 + c0) = wl;
}

// ---------------------------------------------------------------------------
// feats -> transposed split-bf16 Xf[gpx][2][256]. grid = 344. (unchanged)
__global__ __launch_bounds__(256) void k_prep_f(
    const float* __restrict__ f0, const float* __restrict__ f1,
    const float* __restrict__ f2, const float* __restrict__ f3,
    const float* __restrict__ f4, u16* __restrict__ Xf) {
  int blk = blockIdx.x;
  int l, base, nb;
  if (blk < 256)      { l = 0; base = 0;   nb = 64; }
  else if (blk < 320) { l = 1; base = 256; nb = 16; }
  else if (blk < 336) { l = 2; base = 320; nb = 4; }
  else if (blk < 340) { l = 3; base = 336; nb = 1; }
  else                { l = 4; base = 340; nb = 1; }
  int local = blk - base;
  int b = local / nb, chunk = local % nb;
  int S = 64 >> l, SS = S * S;
  int px0 = chunk * 64;
  const float* fin = (l == 0 ? f0 : l == 1 ? f1 : l == 2 ? f2 : l == 3 ? f3 : f4)
                     + (size_t)b * CIN * SS;
  const int jbase[5] = {0, 16384, 20480, 21504, 21760};
  int gpx0 = jbase[l] + b * SS + px0;
  int tid = threadIdx.x;
  __shared__ float sm[16][65];
  int px_r = tid & 63, cr = tid >> 6;
  int px_w = tid >> 2, c4 = (tid & 3) * 4;
  for (int cb = 0; cb < 16; ++cb) {
    __syncthreads();
#pragma unroll
    for (int q = 0; q < 4; ++q) {
      int cl = q * 4 + cr;
      float v = 0.f;
      if (px0 + px_r < SS) v = fin[(size_t)(cb * 16 + cl) * SS + px0 + px_r];
      sm[cl][px_r] = v;
    }
    __syncthreads();
    if (px0 + px_w < SS) {
      u16 hh[4], ll[4];
#pragma unroll
      for (int e = 0; e < 4; ++e) {
        float v = sm[c4 + e][px_w];
        hh[e] = f2bf(v); ll[e] = f2bf(v - bf2f(hh[e]));
      }
      uint2 wh, wl;
      wh.x = (unsigned)hh[0] | ((unsigned)hh[1] << 16); wh.y = (unsigned)hh[2] | ((unsigned)hh[3] << 16);
      wl.x = (unsigned)ll[0] | ((unsigned)ll[1] << 16); wl.y = (unsigned)ll[2] | ((unsigned)ll[3] << 16);
      u16* dst = Xf + (size_t)(gpx0 + px_w) * 512 + cb * 16 + c4;
      *reinterpret_cast<uint2*>(dst) = wh;
      *reinterpret_cast<uint2*>(dst + 256) = wl;
    }
  }
}

// ---------------------------------------------------------------------------
// MEGA: per block (l, bn, jt of 32 j): QK^T scores -> softmax -> p in LDS ->
// fa written straight to out -> aggn MFMA tiles. grid = 1600 x 256.
__global__ __launch_bounds__(256) void k_mega(
    const float* __restrict__ kqall, const u16* __restrict__ vt2,
    float* __restrict__ out, float* __restrict__ aggn_all) {
  int blk = blockIdx.x;
  int l = blk / 320;
  int r = blk % 320;
  int bn = r >> 3, jt = r & 7;
  int b = bn / NCLS, n = bn % NCLS;
  int t = threadIdx.x;
  int iq = t >> 5, jl = t & 31;
  int j = jt * 32 + jl;

  __shared__ float buf[32 * 257];   // phase A: kq staging [k][i]; phase B: p [jl][i] (stride 257)
  __shared__ float red[512];

  const float* ktb = kqall + 20 * KD * HW;
  float ktr[KD];
#pragma unroll
  for (int k = 0; k < KD; ++k) ktr[k] = ktb[((size_t)n * KD + k) * HW + j];
  const float* kqb = kqall + (size_t)(l * 4 + b) * KD * HW;
  for (int s = t; s < KD * HW; s += 256) buf[s] = kqb[s];
  __syncthreads();

  float v[32];
#pragma unroll
  for (int ii = 0; ii < 32; ++ii) v[ii] = 0.f;
  for (int k = 0; k < KD; ++k) {
    float a = ktr[k];
    const float4* q4 = (const float4*)&buf[k * 256 + iq * 32];
#pragma unroll
    for (int q = 0; q < 8; ++q) {
      float4 u = q4[q];
      v[q * 4 + 0] += u.x * a; v[q * 4 + 1] += u.y * a;
      v[q * 4 + 2] += u.z * a; v[q * 4 + 3] += u.w * a;
    }
  }
  float ml = -1e30f;
#pragma unroll
  for (int ii = 0; ii < 32; ++ii) ml = fmaxf(ml, v[ii]);
  float sl = 0.f;
#pragma unroll
  for (int ii = 0; ii < 32; ++ii) sl += __expf(v[ii] - ml);
  red[t] = ml;
  red[256 + t] = sl;
  __syncthreads();          // also guarantees all buf(kq) reads done
  float M = -1e30f;
#pragma unroll
  for (int q = 0; q < 8; ++q) M = fmaxf(M, red[q * 32 + jl]);
  float S = 0.f;
#pragma unroll
  for (int q = 0; q < 8; ++q) S += red[256 + q * 32 + jl] * __expf(red[q * 32 + jl] - M);
  float inv = 1.0f / S;
  // normalized p -> buf[jl][i], stride 257 (bank-safe)
#pragma unroll
  for (int ii = 0; ii < 32; ++ii)
    buf[jl * 257 + iq * 32 + ii] = __expf(v[ii] - M) * inv;
  __syncthreads();

  // ---- fa: bilinear over i-grid, direct to out ----
  int S_ = 64 >> l, shift = 6 - l, SS = S_ * S_;
  const size_t fa_off[5] = {5586944, 47529984, 58015744, 60637184, 61292544};
  float* ob = out + fa_off[l] + ((size_t)bn * HW + jt * 32) * SS;
  int tot = SS << 5;
  for (int base = t * 4; base < tot; base += 1024) {
    int jj = base >> (2 * shift);
    int rest = base & (SS - 1);
    int X0 = rest & (S_ - 1), Y = rest >> shift;
    float cyf = (float)(Y * 15) / (float)(S_ - 1);
    int ylo = imin((int)cyf, 14); float fy = cyf - (float)ylo;
    const float* prow = &buf[jj * 257];
    float4 rv; float* rr = (float*)&rv;
#pragma unroll
    for (int t4 = 0; t4 < 4; ++t4) {
      int X = X0 + t4;
      float cxf = (float)(X * 15) / (float)(S_ - 1);
      int xlo = imin((int)cxf, 14); float fx = cxf - (float)xlo;
      int i00 = ylo * 16 + xlo;
      float v0 = prow[i00],      v1 = prow[i00 + 1];
      float v2 = prow[i00 + 16], v3 = prow[i00 + 17];
      rr[t4] = (1.f - fy) * ((1.f - fx) * v0 + fx * v1)
             + fy * ((1.f - fx) * v2 + fx * v3);
    }
    *(float4*)(ob + (size_t)jj * SS + rest) = rv;
  }

  // ---- aggn: [128 c][32 j] via MFMA; wave w owns c-tiles {2w, 2w+1} ----
  int w = t >> 6, lane = t & 63;
  int row = lane & 15, kg = lane >> 4;
  f4v acc[2][2] = {{{0.f,0.f,0.f,0.f},{0.f,0.f,0.f,0.f}},
                   {{0.f,0.f,0.f,0.f},{0.f,0.f,0.f,0.f}}};
  for (int kc = 0; kc < 8; ++kc) {
    bf8v ah[2], al[2];
#pragma unroll
    for (int ctl = 0; ctl < 2; ++ctl) {
      int ct = w * 2 + ctl;
      const u16* vh = vt2 + ((size_t)n * VD + ct * 16 + row) * 256 + kc * 32 + kg * 8;
      ah[ctl] = *reinterpret_cast<const bf8v*>(vh);
      al[ctl] = *reinterpret_cast<const bf8v*>(vh + 327680);
    }
#pragma unroll
    for (int jt2 = 0; jt2 < 2; ++jt2) {
      union { u16 u[8]; bf8v v8; } Bh, Bl;
#pragma unroll
      for (int e = 0; e < 8; ++e) {
        float f = buf[(jt2 * 16 + row) * 257 + kc * 32 + kg * 8 + e];
        u16 h = f2bf(f);
        Bh.u[e] = h; Bl.u[e] = f2bf(f - bf2f(h));
      }
#pragma unroll
      for (int ctl = 0; ctl < 2; ++ctl) {
        acc[ctl][jt2] = mfma16(ah[ctl], Bh.v8, acc[ctl][jt2]);
        acc[ctl][jt2] = mfma16(ah[ctl], Bl.v8, acc[ctl][jt2]);
        acc[ctl][jt2] = mfma16(al[ctl], Bh.v8, acc[ctl][jt2]);
      }
    }
  }
  float* ab = aggn_all + (size_t)(l * 40 + bn) * VD * HW;
#pragma unroll
  for (int ctl = 0; ctl < 2; ++ctl)
#pragma unroll
    for (int jt2 = 0; jt2 < 2; ++jt2)
#pragma unroll
      for (int i = 0; i < 4; ++i)
        ab[(size_t)(w * 32 + ctl * 16 + kg * 4 + i) * HW + jt * 32 + jt2 * 16 + row]
            = acc[ctl][jt2][i];
}

// ---------------------------------------------------------------------------
// f16_all[img][128+c][j] = sum_n aggn_all[(img_l*40 + img_b*10 + n)][c][j].
// grid = 2560.
__global__ __launch_bounds__(256) void k_aggred_all(
    const float* __restrict__ aggn_all, float* __restrict__ f16_all) {
  int idx = blockIdx.x * 256 + threadIdx.x;
  int j = idx & 255;
  int c = (idx >> 8) & 127;
  int img = idx >> 15;                    // 0..19
  int bn0 = (img >> 2) * 40 + (img & 3) * 10;
  float s = 0.f;
#pragma unroll
  for (int n = 0; n < NCLS; ++n)
    s += aggn_all[((size_t)(bn0 + n) * VD + c) * HW + j];
  f16_all[((size_t)img * CIN + VD + c) * HW + j] = s;
}

// ---------------------------------------------------------------------------
// g16_all[l,b,oc,j] = sum_c cw[oc,256+c]*(gamma[l,c]*BNC)*f16_all[l,b,c,j]
__global__ __launch_bounds__(256) void k_g16_all(
    const float* __restrict__ f16_all, const float* __restrict__ cw,
    const float* __restrict__ gamma, float* __restrict__ g16_all) {
  int blk = blockIdx.x;
  int l = blk >> 7, b = (blk >> 5) & 3, ocg = blk & 31;
  int j = threadIdx.x;
  const float* f16 = f16_all + (size_t)(l * 4 + b) * CIN * HW;
  const float* gm  = gamma + l * CIN;
  float acc[8] = {};
  for (int c = 0; c < CIN; ++c) {
    float fv = f16[(size_t)c * HW + j] * (gm[c] * BNC);
#pragma unroll
    for (int o = 0; o < 8; ++o)
      acc[o] += cw[(size_t)(ocg * 8 + o) * 512 + 256 + c] * fv;
  }
  for (int o = 0; o < 8; ++o)
    g16_all[((size_t)(l * 4 + b) * CIN + ocg * 8 + o) * HW + j] = acc[o];
}

// cb[l,oc] = combine_b[oc] + sum_c cw[oc,256+c]*beta[l,c].  grid=5, block=256
__global__ __launch_bounds__(256) void k_cb(
    const float* __restrict__ cw, const float* __restrict__ cbias,
    const float* __restrict__ beta, float* __restrict__ cb) {
  int l = blockIdx.x, oc = threadIdx.x;
  float s = cbias[oc];
  for (int c = 0; c < CIN; ++c)
    s += cw[(size_t)oc * 512 + 256 + c] * beta[l * CIN + c];
  cb[l * CIN + oc] = s;
}

// ---------------------------------------------------------------------------
// Resize g16 (+cb) into out (base term). block = (img, ocg of 16). grid=320.
__global__ __launch_bounds__(256) void k_rg(
    const float* __restrict__ g16_all, const float* __restrict__ cb_all,
    float* __restrict__ out) {
  int img = blockIdx.x >> 4, ocg = blockIdx.x & 15;
  int l = img >> 2, b = img & 3;
  int tid = threadIdx.x;
  __shared__ float ld[16][257];
  const float* gb = g16_all + ((size_t)img * CIN + ocg * 16) * HW;
  for (int t2 = tid; t2 < 4096; t2 += 256)
    ld[t2 >> 8][t2 & 255] = gb[t2];
  __syncthreads();
  int S = 64 >> l, shift = 6 - l, SS = S * S;
  const size_t ooff[5] = {0, 4194304, 5242880, 5505024, 5570560};
  float* ob = out + ooff[l] + ((size_t)b * CIN + ocg * 16) * SS;
  int tot = SS << 4;
  for (int basei = tid * 4; basei < tot; basei += 1024) {
    int oc = basei >> (2 * shift);
    int rest = basei & (SS - 1);
    int X0 = rest & (S - 1), Y = rest >> shift;
    float cyf = (float)(Y * 15) / (float)(S - 1);
    int ylo = imin((int)cyf, 14); float fy = cyf - (float)ylo;
    float cbs = cb_all[l * CIN + ocg * 16 + oc];
    float4 rv; float* rr = (float*)&rv;
#pragma unroll
    for (int t4 = 0; t4 < 4; ++t4) {
      int X = X0 + t4;
      float cxf = (float)(X * 15) / (float)(S - 1);
      int xlo = imin((int)cxf, 14); float fx = cxf - (float)xlo;
      int i00 = ylo * 16 + xlo;
      float v0 = ld[oc][i00],      v1 = ld[oc][i00 + 1];
      float v2 = ld[oc][i00 + 16], v3 = ld[oc][i00 + 17];
      rr[t4] = (1.f - fy) * ((1.f - fx) * v0 + fx * v1)
             + fy * ((1.f - fx) * v2 + fx * v3) + cbs;
    }
    *(float4*)(ob + (size_t)oc * SS + rest) = rv;
  }
}

// ---------------------------------------------------------------------------
// out += cw[:, :256] . f  (MFMA GEMM over all level images). grid = 5456.
__global__ __launch_bounds__(256) void k_out_mfma(
    const u16* __restrict__ cwA, const u16* __restrict__ Xf,
    float* __restrict__ out) {
  int wid = blockIdx.x * 4 + (threadIdx.x >> 6);
  int lane = threadIdx.x & 63;
  int pt = wid >> 4, octile = wid & 15;
  int l, lb, tl;
  if (pt < 1024)      { l = 0; lb = 0;    tl = 256; }
  else if (pt < 1280) { l = 1; lb = 1024; tl = 64; }
  else if (pt < 1344) { l = 2; lb = 1280; tl = 16; }
  else if (pt < 1360) { l = 3; lb = 1344; tl = 4; }
  else                { l = 4; lb = 1360; tl = 1; }
  int rem = pt - lb;
  int b = rem / tl;
  int pxin = (rem % tl) * 16;
  const int jbase[5] = {0, 16384, 20480, 21504, 21760};
  const size_t ooff[5] = {0, 4194304, 5242880, 5505024, 5570560};
  int S = 64 >> l, SS = S * S;
  int row = lane & 15, kg = lane >> 4;
  int gpx = jbase[l] + b * SS + pxin + row;

  const u16* Ah = cwA + ((size_t)(octile * 16 + row)) * 256 + kg * 8;
  const u16* Al = Ah + 65536;
  const u16* Bh = Xf + (size_t)gpx * 512 + kg * 8;
  const u16* Bl = Bh + 256;
  f4v acc = {0.f, 0.f, 0.f, 0.f};
#pragma unroll
  for (int kc = 0; kc < 8; ++kc) {
    bf8v ah = *reinterpret_cast<const bf8v*>(Ah + kc * 32);
    bf8v al = *reinterpret_cast<const bf8v*>(Al + kc * 32);
    bf8v bh = *reinterpret_cast<const bf8v*>(Bh + kc * 32);
    bf8v bl = *reinterpret_cast<const bf8v*>(Bl + kc * 32);
    acc = mfma16(ah, bh, acc);
    acc = mfma16(ah, bl, acc);
    acc = mfma16(al, bh, acc);
  }
  float* ob = out + ooff[l] + ((size_t)b * CIN + octile * 16) * SS + pxin + row;
#pragma unroll
  for (int i = 0; i < 4; ++i) {
    float* po = ob + (size_t)(kg * 4 + i) * SS;
    *po += acc[i];
  }
}

// ===========================================================================
extern "C" void kernel_launch(void* const* d_in, const int* in_sizes, int n_in,
                              void* d_out, int out_size, void* d_ws, size_t ws_size,
                              hipStream_t stream) {
  const float* feat[5];
  for (int l = 0; l < 5; ++l) feat[l] = (const float*)d_in[l];
  const float* att   = (const float*)d_in[5];
  const float* ktw   = (const float*)d_in[6];
  const float* ktb   = (const float*)d_in[7];
  const float* vtw   = (const float*)d_in[8];
  const float* vtb   = (const float*)d_in[9];
  const float* kqw   = (const float*)d_in[10];
  const float* kqb   = (const float*)d_in[11];
  const float* vqw   = (const float*)d_in[12];
  const float* vqb   = (const float*)d_in[13];
  const float* gamma = (const float*)d_in[14];
  const float* beta  = (const float*)d_in[15];
  const float* cw    = (const float*)d_in[16];
  const float* cbias = (const float*)d_in[17];
  float* out = (float*)d_out;

  // workspace layout (floats), total 14,419,200 fl = 57.7 MB
  float* ws      = (float*)d_ws;
  float* kqall   = ws;                     // [30][32][256]   245760
  float* vt      = ws + 245760;            // [10][128][256]  327680
  float* f16_all = ws + 573440;            // [20][256][256]  1310720
  u16*   vt2     = (u16*)(ws + 1884160);   // [2][10][128][256] u16 = 327680 fl
  u16*   cwA     = (u16*)(ws + 2211840);   // [2][256][256] u16     = 65536 fl
  float* cb      = ws + 2277376;           // [5][256]              = 1280
  u16*   Xf      = (u16*)(ws + 2278656);   // [21824][2][256] u16   = 5586944 fl
  float* R       = ws + 7865600;           // 6,553,600 fl shared region
  // conv phase: X | Awv | Awk (4,700,160 fl)
  u16*   X       = (u16*)R;                    // 4976640 u16 = 2488320 fl
  u16*   Awv     = (u16*)(R + 2488320);        // 3538944 u16 = 1769472 fl
  u16*   Awk     = (u16*)(R + 4257792);        //  884736 u16 = 442368 fl
  // mega phase: aggn_all [200][128][256] = 6553600 fl
  float* aggn_all = R;
  // phase 3: g16_all (aggn dead after aggred)
  float* g16_all = R;

  // Phase 1: preps + MFMA convs
  k_prep_x<<<540, 256, 0, stream>>>(
      feat[0], feat[1], feat[2], feat[3], feat[4], att, X);
  k_prep_w<<<1080, 256, 0, stream>>>(vqw, vtw, kqw, ktw, Awv, Awk);
  k_prep_f<<<344, 256, 0, stream>>>(
      feat[0], feat[1], feat[2], feat[3], feat[4], Xf);
  k_prep_cw<<<64, 256, 0, stream>>>(cw, cwA);
  k_cb<<<5, 256, 0, stream>>>(cw, cbias, beta, cb);
  k_conv_mfma<<<600, 256, 0, stream>>>(
      X, Awv, Awk, kqall, vt, f16_all, vqb, vtb, kqb, ktb);
  k_prep_vt<<<320, 256, 0, stream>>>(vt, vt2);

  // Phase 2: fused p-chain, all levels in one launch
  k_mega<<<1600, 256, 0, stream>>>(kqall, vt2, out, aggn_all);
  k_aggred_all<<<2560, 256, 0, stream>>>(aggn_all, f16_all);

  // Phase 3: combine
  k_g16_all<<<5 * 4 * 32, 256, 0, stream>>>(f16_all, cw, gamma, g16_all);
  k_rg<<<320, 256, 0, stream>>>(g16_all, cb, out);
  k_out_mfma<<<5456, 256, 0, stream>>>(cwA, Xf, out);
}

// Round 9
// 403.460 us; speedup vs baseline: 1.4658x; 1.0166x over previous
//
#include <hip/hip_runtime.h>

// Problem constants
constexpr int CIN   = 256;   // feature channels
constexpr int KD    = 32;    // key dim
constexpr int VD    = 128;   // value dim
constexpr int NCLS  = 10;
constexpr int BS    = 4;
constexpr int HW    = 256;   // 16*16
constexpr float BNC = 0.9999950000374997f; // 1/sqrt(1+1e-5)

typedef unsigned short u16;
typedef __attribute__((ext_vector_type(8))) __bf16 bf8v;
typedef __attribute__((ext_vector_type(4))) float f4v;

static __device__ __forceinline__ int imin(int a, int b) { return a < b ? a : b; }

static __device__ __forceinline__ u16 f2bf(float v) {
  union { float f; unsigned u; } x; x.f = v;
  unsigned r = x.u + 0x7FFFu + ((x.u >> 16) & 1u);
  return (u16)(r >> 16);
}
static __device__ __forceinline__ float bf2f(u16 h) {
  union { unsigned u; float f; } x; x.u = ((unsigned)h) << 16;
  return x.f;
}

static __device__ __forceinline__ f4v mfma16(bf8v a, bf8v b, f4v c) {
  return __builtin_amdgcn_mfma_f32_16x16x32_bf16(a, b, c, 0, 0, 0);
}

__constant__ const int c_jbase[5] = {0, 16384, 20480, 21504, 21760};

// ---------------------------------------------------------------------------
// Prep: transpose features -> Xf[gpx][2][256] (levels) and att -> Xr[20+n]
// (templates, already 16x16). grid = 344 + 40 = 384.
__global__ __launch_bounds__(256) void k_prep_f(
    const float* __restrict__ f0, const float* __restrict__ f1,
    const float* __restrict__ f2, const float* __restrict__ f3,
    const float* __restrict__ f4, const float* __restrict__ att,
    u16* __restrict__ Xf, u16* __restrict__ Xr) {
  int blk = blockIdx.x;
  const float* fin; u16* dstbase; int SS, px0;
  if (blk < 344) {
    int l, base, nb;
    if (blk < 256)      { l = 0; base = 0;   nb = 64; }
    else if (blk < 320) { l = 1; base = 256; nb = 16; }
    else if (blk < 336) { l = 2; base = 320; nb = 4; }
    else if (blk < 340) { l = 3; base = 336; nb = 1; }
    else                { l = 4; base = 340; nb = 1; }
    int local = blk - base;
    int b = local / nb, chunk = local % nb;
    int S = 64 >> l; SS = S * S;
    px0 = chunk * 64;
    fin = (l == 0 ? f0 : l == 1 ? f1 : l == 2 ? f2 : l == 3 ? f3 : f4)
          + (size_t)b * CIN * SS;
    dstbase = Xf + (size_t)(c_jbase[l] + b * SS) * 512;
  } else {
    int a = blk - 344;
    int imgA = a >> 2, chunk = a & 3;
    SS = 256; px0 = chunk * 64;
    fin = att + (size_t)imgA * CIN * 256;
    dstbase = Xr + (size_t)(20 + imgA) * 131072;
  }
  int tid = threadIdx.x;
  __shared__ float sm[16][65];
  int px_r = tid & 63, cr = tid >> 6;
  int px_w = tid >> 2, c4 = (tid & 3) * 4;
  for (int cbk = 0; cbk < 16; ++cbk) {
    __syncthreads();
#pragma unroll
    for (int q = 0; q < 4; ++q) {
      int cl = q * 4 + cr;
      float v = 0.f;
      if (px0 + px_r < SS) v = fin[(size_t)(cbk * 16 + cl) * SS + px0 + px_r];
      sm[cl][px_r] = v;
    }
    __syncthreads();
    if (px0 + px_w < SS) {
      u16 hh[4], ll[4];
#pragma unroll
      for (int e = 0; e < 4; ++e) {
        float v = sm[c4 + e][px_w];
        hh[e] = f2bf(v); ll[e] = f2bf(v - bf2f(hh[e]));
      }
      uint2 wh, wl;
      wh.x = (unsigned)hh[0] | ((unsigned)hh[1] << 16); wh.y = (unsigned)hh[2] | ((unsigned)hh[3] << 16);
      wl.x = (unsigned)ll[0] | ((unsigned)ll[1] << 16); wl.y = (unsigned)ll[2] | ((unsigned)ll[3] << 16);
      u16* dst = dstbase + (size_t)(px0 + px_w) * 512 + cbk * 16 + c4;
      *reinterpret_cast<uint2*>(dst) = wh;
      *reinterpret_cast<uint2*>(dst + 256) = wl;
    }
  }
}

// ---------------------------------------------------------------------------
// Level imgs: bilinear-resize Xf rows -> Xr[img][px][2][256]. grid = 320.
// Also zeroes zrow (block 0).
__global__ __launch_bounds__(256) void k_prep_xr(
    const u16* __restrict__ Xf, u16* __restrict__ Xr, u16* __restrict__ zrow) {
  int blk = blockIdx.x;
  int img = blk >> 4, yr = blk & 15;
  int l = img >> 2, b = img & 3;
  int S = 64 >> l, SS = S * S;
  int c = threadIdx.x;
  if (blk == 0) { zrow[c] = 0; zrow[256 + c] = 0; }
  float cyf = (float)(yr * (S - 1)) / 15.0f;
  int ylo = imin((int)cyf, S - 2); float fy = cyf - (float)ylo;
  u16* dst = Xr + ((size_t)img * 256 + yr * 16) * 512;
  const u16* srcb = Xf + (size_t)(c_jbase[l] + b * SS) * 512;
  for (int x = 0; x < 16; ++x) {
    float cxf = (float)(x * (S - 1)) / 15.0f;
    int xlo = imin((int)cxf, S - 2); float fx = cxf - (float)xlo;
    const u16* r00 = srcb + (size_t)(ylo * S + xlo) * 512;
    const u16* r10 = srcb + (size_t)((ylo + 1) * S + xlo) * 512;
    float v00 = bf2f(r00[c]) + bf2f(r00[256 + c]);
    float v01 = bf2f(r00[512 + c]) + bf2f(r00[768 + c]);
    float v10 = bf2f(r10[c]) + bf2f(r10[256 + c]);
    float v11 = bf2f(r10[512 + c]) + bf2f(r10[768 + c]);
    float v = (1.f - fy) * ((1.f - fx) * v00 + fx * v01)
            + fy * ((1.f - fx) * v10 + fx * v11);
    u16 h = f2bf(v);
    dst[x * 512 + c] = h;
    dst[x * 512 + 256 + c] = f2bf(v - bf2f(h));
  }
}

// ---------------------------------------------------------------------------
// Prep conv weights into MFMA-A fragment order, split bf16 hi/lo. grid=1080.
__global__ __launch_bounds__(256) void k_prep_w(
    const float* __restrict__ vqw, const float* __restrict__ vtw,
    const float* __restrict__ kqw, const float* __restrict__ ktw,
    u16* __restrict__ Awv, u16* __restrict__ Awk) {
  int gid = blockIdx.x * 256 + threadIdx.x;
  int lane = gid & 63;
  int grp = gid >> 6;
  const float* src; u16* dst; int kc;
  if (grp < 3456) {
    kc = grp % 72; int ot = (grp / 72) % 8; int sid = grp / (72 * 8);
    src = (sid < 5 ? vqw + (size_t)sid * VD * 2304 : vtw) + (size_t)(ot * 16 + (lane & 15)) * 2304;
    dst = Awv + (size_t)grp * 1024;
  } else {
    int g2 = grp - 3456;
    kc = g2 % 72; int ot = (g2 / 72) % 2; int sid = g2 / 144;
    src = (sid < 5 ? kqw + (size_t)sid * KD * 2304 : ktw) + (size_t)(ot * 16 + (lane & 15)) * 2304;
    dst = Awk + (size_t)g2 * 1024;
  }
  int q0 = (lane >> 4) * 8;
  int t = kc >> 3, c0 = (kc & 7) * 32;
#pragma unroll
  for (int i = 0; i < 8; ++i) {
    int c = c0 + q0 + i;
    float v = src[c * 9 + t];
    u16 h = f2bf(v);
    dst[lane * 8 + i] = h;
    dst[512 + lane * 8 + i] = f2bf(v - bf2f(h));
  }
}

// ---------------------------------------------------------------------------
// cwA (cols 0..255) + cw2A (cols 256..511 with gamma*BNC folded, per level).
// grid = 64 + 320 = 384.
__global__ __launch_bounds__(256) void k_prep_cwg(
    const float* __restrict__ cw, const float* __restrict__ gamma,
    u16* __restrict__ cwA, u16* __restrict__ cw2A) {
  int blk = blockIdx.x;
  if (blk < 64) {
    int gid = blk * 256 + threadIdx.x;
    int oc = gid >> 6, c0 = (gid & 63) * 4;
    float4 v = *reinterpret_cast<const float4*>(cw + (size_t)oc * 512 + c0);
    const float* vv = (const float*)&v;
    u16 h[4], l[4];
#pragma unroll
    for (int e = 0; e < 4; ++e) { h[e] = f2bf(vv[e]); l[e] = f2bf(vv[e] - bf2f(h[e])); }
    uint2 wh, wl;
    wh.x = (unsigned)h[0] | ((unsigned)h[1] << 16); wh.y = (unsigned)h[2] | ((unsigned)h[3] << 16);
    wl.x = (unsigned)l[0] | ((unsigned)l[1] << 16); wl.y = (unsigned)l[2] | ((unsigned)l[3] << 16);
    *reinterpret_cast<uint2*>(cwA + (size_t)oc * 256 + c0) = wh;
    *reinterpret_cast<uint2*>(cwA + 65536 + (size_t)oc * 256 + c0) = wl;
  } else {
    int gid = (blk - 64) * 256 + threadIdx.x;   // 0..81919, x4 elems
    int l = gid / 16384, rem = gid % 16384;
    int oc = rem >> 6, c0 = (rem & 63) * 4;
    u16 h[4], lo[4];
#pragma unroll
    for (int e = 0; e < 4; ++e) {
      int c = c0 + e;
      float v = cw[(size_t)oc * 512 + 256 + c] * (gamma[l * 256 + c] * BNC);
      h[e] = f2bf(v); lo[e] = f2bf(v - bf2f(h[e]));
    }
    uint2 wh, wl;
    wh.x = (unsigned)h[0] | ((unsigned)h[1] << 16); wh.y = (unsigned)h[2] | ((unsigned)h[3] << 16);
    wl.x = (unsigned)lo[0] | ((unsigned)lo[1] << 16); wl.y = (unsigned)lo[2] | ((unsigned)lo[3] << 16);
    *reinterpret_cast<uint2*>(cw2A + (size_t)l * 65536 + oc * 256 + c0) = wh;
    *reinterpret_cast<uint2*>(cw2A + 327680 + (size_t)l * 65536 + oc * 256 + c0) = wl;
  }
}

// cb[l,oc] = combine_b[oc] + sum_c cw[oc,256+c]*beta[l,c].  grid=5.
__global__ __launch_bounds__(256) void k_cb(
    const float* __restrict__ cw, const float* __restrict__ cbias,
    const float* __restrict__ beta, float* __restrict__ cb) {
  int l = blockIdx.x, oc = threadIdx.x;
  float s = cbias[oc];
  for (int c = 0; c < CIN; ++c)
    s += cw[(size_t)oc * 512 + 256 + c] * beta[l * CIN + c];
  cb[l * CIN + oc] = s;
}

// ---------------------------------------------------------------------------
// MFMA conv from Xr (16x16 transposed split-bf16, zero-row for padding).
// grid = 600.
__global__ __launch_bounds__(256) void k_conv_mfma(
    const u16* __restrict__ Xr, const u16* __restrict__ Awv, const u16* __restrict__ Awk,
    const u16* __restrict__ zrow,
    float* __restrict__ kqall, float* __restrict__ vt, float* __restrict__ f16v,
    const float* __restrict__ vqb, const float* __restrict__ vtb,
    const float* __restrict__ kqb, const float* __restrict__ ktb) {
  int wid = blockIdx.x * 4 + (threadIdx.x >> 6);
  int lane = threadIdx.x & 63;
  bool isV = wid < 1920;
  int img, ot, yp;
  if (isV) { img = wid >> 6; int r = wid & 63; ot = r >> 3; yp = r & 7; }
  else     { int j = wid - 1920; img = j >> 4; int r = j & 15; ot = r >> 3; yp = r & 7; }
  int wset = img < 20 ? (img >> 2) : 5;

  const u16* Ab = isV ? Awv + ((size_t)(wset * 8 + ot)) * 72 * 1024
                      : Awk + ((size_t)(wset * 2 + ot)) * 72 * 1024;
  const u16* Xb = Xr + (size_t)img * 131072;
  int xcol = lane & 15, kg = lane >> 4;
  int y0 = yp * 2, y1 = y0 + 1;

  f4v acc0 = {0.f, 0.f, 0.f, 0.f}, acc1 = {0.f, 0.f, 0.f, 0.f};
  for (int t = 0; t < 9; ++t) {
    int dy = (t >= 6) ? 2 : (t >= 3 ? 1 : 0);
    int dx = t - dy * 3;
    int yy0 = y0 + dy - 1, yy1 = yy0 + 1;
    int xx = xcol + dx - 1;
    bool xok = (unsigned)xx < 16u;
    const u16* base0 = (xok && (unsigned)yy0 < 16u)
                       ? Xb + (size_t)(yy0 * 16 + xx) * 512 : zrow;
    const u16* base1 = (xok && (unsigned)yy1 < 16u)
                       ? Xb + (size_t)(yy1 * 16 + xx) * 512 : zrow;
    const u16* Xr0 = base0 + kg * 8;
    const u16* Xr1 = base1 + kg * 8;
    const u16* Ak = Ab + (size_t)t * 8 * 1024 + lane * 8;
#pragma unroll
    for (int cc = 0; cc < 8; ++cc) {
      bf8v ah = *reinterpret_cast<const bf8v*>(Ak + cc * 1024);
      bf8v al = *reinterpret_cast<const bf8v*>(Ak + cc * 1024 + 512);
      bf8v bh0 = *reinterpret_cast<const bf8v*>(Xr0 + cc * 32);
      bf8v bl0 = *reinterpret_cast<const bf8v*>(Xr0 + cc * 32 + 256);
      bf8v bh1 = *reinterpret_cast<const bf8v*>(Xr1 + cc * 32);
      bf8v bl1 = *reinterpret_cast<const bf8v*>(Xr1 + cc * 32 + 256);
      acc0 = mfma16(ah, bh0, acc0);
      acc0 = mfma16(ah, bl0, acc0);
      acc0 = mfma16(al, bh0, acc0);
      acc1 = mfma16(ah, bh1, acc1);
      acc1 = mfma16(ah, bl1, acc1);
      acc1 = mfma16(al, bh1, acc1);
    }
  }

  float scale = 1.f;
  const float* bias;
  float* dst;
  int ocbase = ot * 16;
  if (isV) {
    if (img < 20) { dst = f16v + ((size_t)img * VD + ocbase) * HW; bias = vqb + wset * VD + ocbase; scale = (float)NCLS; }
    else          { dst = vt + ((size_t)(img - 20) * VD + ocbase) * HW; bias = vtb + ocbase; }
  } else {
    if (img < 20) { dst = kqall + ((size_t)img * KD + ocbase) * HW; bias = kqb + wset * KD + ocbase; }
    else          { dst = kqall + (size_t)20 * KD * HW + ((size_t)(img - 20) * KD + ocbase) * HW; bias = ktb + ocbase; }
  }
#pragma unroll
  for (int i = 0; i < 4; ++i) {
    int ocl = kg * 4 + i;
    float bv = bias[ocl];
    dst[(size_t)ocl * HW + y0 * 16 + xcol] = (acc0[i] + bv) * scale;
    dst[(size_t)ocl * HW + y1 * 16 + xcol] = (acc1[i] + bv) * scale;
  }
}

// ---------------------------------------------------------------------------
// vt (f32) -> split bf16 [2][10][128][256]. grid = 320.
__global__ __launch_bounds__(256) void k_prep_vt(
    const float* __restrict__ vt, u16* __restrict__ vt2) {
  int gid = blockIdx.x * 256 + threadIdx.x;
  float4 v = *reinterpret_cast<const float4*>(vt + (size_t)gid * 4);
  const float* vv = (const float*)&v;
  u16 h[4], l[4];
#pragma unroll
  for (int e = 0; e < 4; ++e) { h[e] = f2bf(vv[e]); l[e] = f2bf(vv[e] - bf2f(h[e])); }
  uint2 wh, wl;
  wh.x = (unsigned)h[0] | ((unsigned)h[1] << 16); wh.y = (unsigned)h[2] | ((unsigned)h[3] << 16);
  wl.x = (unsigned)l[0] | ((unsigned)l[1] << 16); wl.y = (unsigned)l[2] | ((unsigned)l[3] << 16);
  *reinterpret_cast<uint2*>(vt2 + (size_t)gid * 4) = wh;
  *reinterpret_cast<uint2*>(vt2 + 327680 + (size_t)gid * 4) = wl;
}

// ---------------------------------------------------------------------------
// MEGA: block = (l, b, npair, jt of 32 j): for n in {2np, 2np+1}:
// QK^T -> softmax -> p in LDS -> fa direct to out -> aggn MFMA (n-summed).
// grid = 800 x 256.
__global__ __launch_bounds__(256) void k_mega(
    const float* __restrict__ kqall, const u16* __restrict__ vt2,
    float* __restrict__ out, float* __restrict__ aggn) {
  int blk = blockIdx.x;
  int l = blk / 160;
  int r = blk % 160;
  int b = r / 40;
  int r2 = r % 40;
  int np = r2 >> 3, jt = r2 & 7;
  int t = threadIdx.x;
  int iq = t >> 5, jl = t & 31;
  int j = jt * 32 + jl;

  __shared__ float buf[8224];   // kq [32][256] staging, then p [32 j][257]
  __shared__ float red[512];

  const float* ktb = kqall + 20 * KD * HW;
  const float* kqb = kqall + (size_t)(l * 4 + b) * KD * HW;

  int S_ = 64 >> l, shift = 6 - l, SS = S_ * S_;
  const size_t fa_off[5] = {5586944, 47529984, 58015744, 60637184, 61292544};

  int w = t >> 6, lane = t & 63;
  int row = lane & 15, kg = lane >> 4;
  f4v acc[2][2] = {{{0.f,0.f,0.f,0.f},{0.f,0.f,0.f,0.f}},
                   {{0.f,0.f,0.f,0.f},{0.f,0.f,0.f,0.f}}};

  for (int half = 0; half < 2; ++half) {
    int n = np * 2 + half;
    int bn = b * NCLS + n;
    __syncthreads();   // buf free (prev p consumed / first iter no-op)
    for (int s = t; s < KD * HW; s += 256) buf[s] = kqb[s];
    float ktr[KD];
#pragma unroll
    for (int k = 0; k < KD; ++k) ktr[k] = ktb[((size_t)n * KD + k) * HW + j];
    __syncthreads();

    float v[32];
#pragma unroll
    for (int ii = 0; ii < 32; ++ii) v[ii] = 0.f;
    for (int k = 0; k < KD; ++k) {
      float a = ktr[k];
      const float4* q4 = (const float4*)&buf[k * 256 + iq * 32];
#pragma unroll
      for (int q = 0; q < 8; ++q) {
        float4 u = q4[q];
        v[q * 4 + 0] += u.x * a; v[q * 4 + 1] += u.y * a;
        v[q * 4 + 2] += u.z * a; v[q * 4 + 3] += u.w * a;
      }
    }
    float ml = -1e30f;
#pragma unroll
    for (int ii = 0; ii < 32; ++ii) ml = fmaxf(ml, v[ii]);
    float sl = 0.f;
#pragma unroll
    for (int ii = 0; ii < 32; ++ii) sl += __expf(v[ii] - ml);
    red[t] = ml;
    red[256 + t] = sl;
    __syncthreads();          // all buf(kq) reads done too
    float M = -1e30f;
#pragma unroll
    for (int q = 0; q < 8; ++q) M = fmaxf(M, red[q * 32 + jl]);
    float Ssum = 0.f;
#pragma unroll
    for (int q = 0; q < 8; ++q) Ssum += red[256 + q * 32 + jl] * __expf(red[q * 32 + jl] - M);
    float inv = 1.0f / Ssum;
#pragma unroll
    for (int ii = 0; ii < 32; ++ii)
      buf[jl * 257 + iq * 32 + ii] = __expf(v[ii] - M) * inv;
    __syncthreads();

    // fa: bilinear over i-grid, direct to out
    float* ob = out + fa_off[l] + ((size_t)bn * HW + jt * 32) * SS;
    int tot = SS << 5;
    for (int base = t * 4; base < tot; base += 1024) {
      int jj = base >> (2 * shift);
      int rest = base & (SS - 1);
      int X0 = rest & (S_ - 1), Y = rest >> shift;
      float cyf = (float)(Y * 15) / (float)(S_ - 1);
      int ylo = imin((int)cyf, 14); float fy = cyf - (float)ylo;
      const float* prow = &buf[jj * 257];
      float4 rv; float* rr = (float*)&rv;
#pragma unroll
      for (int t4 = 0; t4 < 4; ++t4) {
        int X = X0 + t4;
        float cxf = (float)(X * 15) / (float)(S_ - 1);
        int xlo = imin((int)cxf, 14); float fx = cxf - (float)xlo;
        int i00 = ylo * 16 + xlo;
        float v0 = prow[i00],      v1 = prow[i00 + 1];
        float v2 = prow[i00 + 16], v3 = prow[i00 + 17];
        rr[t4] = (1.f - fy) * ((1.f - fx) * v0 + fx * v1)
               + fy * ((1.f - fx) * v2 + fx * v3);
      }
      *(float4*)(ob + (size_t)jj * SS + rest) = rv;
    }

    // aggn MFMA accumulate (summed over the 2 n's)
    for (int kc = 0; kc < 8; ++kc) {
      bf8v ah[2], al[2];
#pragma unroll
      for (int ctl = 0; ctl < 2; ++ctl) {
        int ct = w * 2 + ctl;
        const u16* vh = vt2 + ((size_t)n * VD + ct * 16 + row) * 256 + kc * 32 + kg * 8;
        ah[ctl] = *reinterpret_cast<const bf8v*>(vh);
        al[ctl] = *reinterpret_cast<const bf8v*>(vh + 327680);
      }
#pragma unroll
      for (int jt2 = 0; jt2 < 2; ++jt2) {
        union { u16 u[8]; bf8v v8; } Bh, Bl;
#pragma unroll
        for (int e = 0; e < 8; ++e) {
          float f = buf[(jt2 * 16 + row) * 257 + kc * 32 + kg * 8 + e];
          u16 h = f2bf(f);
          Bh.u[e] = h; Bl.u[e] = f2bf(f - bf2f(h));
        }
#pragma unroll
        for (int ctl = 0; ctl < 2; ++ctl) {
          acc[ctl][jt2] = mfma16(ah[ctl], Bh.v8, acc[ctl][jt2]);
          acc[ctl][jt2] = mfma16(ah[ctl], Bl.v8, acc[ctl][jt2]);
          acc[ctl][jt2] = mfma16(al[ctl], Bh.v8, acc[ctl][jt2]);
        }
      }
    }
  }

  float* ab = aggn + (size_t)(l * 20 + b * 5 + np) * VD * HW;
#pragma unroll
  for (int ctl = 0; ctl < 2; ++ctl)
#pragma unroll
    for (int jt2 = 0; jt2 < 2; ++jt2)
#pragma unroll
      for (int i = 0; i < 4; ++i)
        ab[(size_t)(w * 32 + ctl * 16 + kg * 4 + i) * HW + jt * 32 + jt2 * 16 + row]
            = acc[ctl][jt2][i];
}

// ---------------------------------------------------------------------------
// Fuse: fsT[img][j][2][256c] (split bf16) from f16v (c<128, vq*10) and
// n-pair-summed aggn (c>=128). grid = 320 (img, jc of 16).
__global__ __launch_bounds__(256) void k_fuse_fs(
    const float* __restrict__ f16v, const float* __restrict__ aggn,
    u16* __restrict__ fsT) {
  int blk = blockIdx.x;
  int img = blk >> 4, jc = blk & 15;
  int j0 = jc * 16;
  int l = img >> 2, b = img & 3;
  int tid = threadIdx.x;
  __shared__ float fs[256][17];
  for (int pass = 0; pass < 16; ++pass) {
    int cc = pass * 16 + (tid >> 4);
    int jj = tid & 15;
    float v;
    if (cc < 128) {
      v = f16v[((size_t)img * VD + cc) * HW + j0 + jj];
    } else {
      const float* ab = aggn + ((size_t)(l * 20 + b * 5) * VD + cc - 128) * HW + j0 + jj;
      v = 0.f;
#pragma unroll
      for (int npx = 0; npx < 5; ++npx) v += ab[(size_t)npx * VD * HW];
    }
    fs[cc][jj] = v;
  }
  __syncthreads();
  int j = tid >> 4, cg = (tid & 15) * 16;
  u16* dst = fsT + ((size_t)img * 256 + j0 + j) * 512 + cg;
#pragma unroll
  for (int e = 0; e < 16; ++e) {
    float v = fs[cg + e][j];
    u16 h = f2bf(v);
    dst[e] = h;
    dst[256 + e] = f2bf(v - bf2f(h));
  }
}

// ---------------------------------------------------------------------------
// g16 via MFMA: g16[img][oc][j] = sum_c cw2_l[oc][c] * fs[img][c][j].
// wave = (img, octile, jt). grid = 1280.
__global__ __launch_bounds__(256) void k_g16_mfma(
    const u16* __restrict__ cw2A, const u16* __restrict__ fsT,
    float* __restrict__ g16_all) {
  int wid = blockIdx.x * 4 + (threadIdx.x >> 6);   // 0..5119
  int lane = threadIdx.x & 63;
  int img = wid >> 8;
  int r = wid & 255;
  int octile = r >> 4, jt = r & 15;
  int l = img >> 2;
  int row = lane & 15, kg = lane >> 4;
  const u16* Ah = cw2A + (size_t)l * 65536 + (octile * 16 + row) * 256 + kg * 8;
  const u16* Al = Ah + 327680;
  const u16* Bh = fsT + ((size_t)img * 256 + jt * 16 + row) * 512 + kg * 8;
  const u16* Bl = Bh + 256;
  f4v acc = {0.f, 0.f, 0.f, 0.f};
#pragma unroll
  for (int kc = 0; kc < 8; ++kc) {
    bf8v ah = *reinterpret_cast<const bf8v*>(Ah + kc * 32);
    bf8v al = *reinterpret_cast<const bf8v*>(Al + kc * 32);
    bf8v bh = *reinterpret_cast<const bf8v*>(Bh + kc * 32);
    bf8v bl = *reinterpret_cast<const bf8v*>(Bl + kc * 32);
    acc = mfma16(ah, bh, acc);
    acc = mfma16(ah, bl, acc);
    acc = mfma16(al, bh, acc);
  }
#pragma unroll
  for (int i = 0; i < 4; ++i)
    g16_all[((size_t)img * CIN + octile * 16 + kg * 4 + i) * HW + jt * 16 + row] = acc[i];
}

// ---------------------------------------------------------------------------
// Final: out = cw[:, :256].f (MFMA) + bilinear(g16) + cb. grid = 5456.
__global__ __launch_bounds__(256) void k_out_final(
    const u16* __restrict__ cwA, const u16* __restrict__ Xf,
    const float* __restrict__ g16_all, const float* __restrict__ cb_all,
    float* __restrict__ out) {
  int wid = blockIdx.x * 4 + (threadIdx.x >> 6);
  int lane = threadIdx.x & 63;
  int pt = wid >> 4, octile = wid & 15;
  int l, lb, tl;
  if (pt < 1024)      { l = 0; lb = 0;    tl = 256; }
  else if (pt < 1280) { l = 1; lb = 1024; tl = 64; }
  else if (pt < 1344) { l = 2; lb = 1280; tl = 16; }
  else if (pt < 1360) { l = 3; lb = 1344; tl = 4; }
  else                { l = 4; lb = 1360; tl = 1; }
  int rem = pt - lb;
  int b = rem / tl;
  int pxin = (rem % tl) * 16;
  const size_t ooff[5] = {0, 4194304, 5242880, 5505024, 5570560};
  int S = 64 >> l, SS = S * S, shift = 6 - l;
  int row = lane & 15, kg = lane >> 4;
  int gpx = c_jbase[l] + b * SS + pxin + row;

  const u16* Ah = cwA + ((size_t)(octile * 16 + row)) * 256 + kg * 8;
  const u16* Al = Ah + 65536;
  const u16* Bh = Xf + (size_t)gpx * 512 + kg * 8;
  const u16* Bl = Bh + 256;
  f4v acc = {0.f, 0.f, 0.f, 0.f};
#pragma unroll
  for (int kc = 0; kc < 8; ++kc) {
    bf8v ah = *reinterpret_cast<const bf8v*>(Ah + kc * 32);
    bf8v al = *reinterpret_cast<const bf8v*>(Al + kc * 32);
    bf8v bh = *reinterpret_cast<const bf8v*>(Bh + kc * 32);
    bf8v bl = *reinterpret_cast<const bf8v*>(Bl + kc * 32);
    acc = mfma16(ah, bh, acc);
    acc = mfma16(ah, bl, acc);
    acc = mfma16(al, bh, acc);
  }

  int px = pxin + row;
  int Xc = px & (S - 1), Y = px >> shift;
  float cyf = (float)(Y * 15) / (float)(S - 1);
  int ylo = imin((int)cyf, 14); float fy = cyf - (float)ylo;
  float cxf = (float)(Xc * 15) / (float)(S - 1);
  int xlo = imin((int)cxf, 14); float fx = cxf - (float)xlo;
  int i00 = ylo * 16 + xlo;
  const float* gbase = g16_all + ((size_t)(l * 4 + b) * CIN + octile * 16 + kg * 4) * HW;
  float* ob = out + ooff[l] + ((size_t)b * CIN + octile * 16) * SS + px;
#pragma unroll
  for (int i = 0; i < 4; ++i) {
    const float* g = gbase + (size_t)i * HW + i00;
    float v0 = g[0], v1 = g[1], v2 = g[16], v3 = g[17];
    float bil = (1.f - fy) * ((1.f - fx) * v0 + fx * v1)
              + fy * ((1.f - fx) * v2 + fx * v3);
    ob[(size_t)(kg * 4 + i) * SS] = acc[i] + bil + cb_all[l * CIN + octile * 16 + kg * 4 + i];
  }
}

// ===========================================================================
extern "C" void kernel_launch(void* const* d_in, const int* in_sizes, int n_in,
                              void* d_out, int out_size, void* d_ws, size_t ws_size,
                              hipStream_t stream) {
  const float* feat[5];
  for (int l = 0; l < 5; ++l) feat[l] = (const float*)d_in[l];
  const float* att   = (const float*)d_in[5];
  const float* ktw   = (const float*)d_in[6];
  const float* ktb   = (const float*)d_in[7];
  const float* vtw   = (const float*)d_in[8];
  const float* vtb   = (const float*)d_in[9];
  const float* kqw   = (const float*)d_in[10];
  const float* kqb   = (const float*)d_in[11];
  const float* vqw   = (const float*)d_in[12];
  const float* vqb   = (const float*)d_in[13];
  const float* gamma = (const float*)d_in[14];
  const float* beta  = (const float*)d_in[15];
  const float* cw    = (const float*)d_in[16];
  const float* cbias = (const float*)d_in[17];
  float* out = (float*)d_out;

  // workspace layout (floats), total 11,797,760 fl = 47.2 MB
  float* ws    = (float*)d_ws;
  float* kqall = ws;                     // [30][32][256]        245760
  float* f16v  = ws + 245760;            // [20][128][256]       655360 (vq*10)
  u16*   vt2   = (u16*)(ws + 901120);    // [2][10][128][256]u16 327680 fl
  u16*   cwA   = (u16*)(ws + 1228800);   // [2][256][256] u16    65536 fl
  u16*   cw2A  = (u16*)(ws + 1294336);   // [2][5][256][256]u16  327680 fl
  float* cb    = ws + 1622016;           // [5][256]             1280
  u16*   Xf    = (u16*)(ws + 1623296);   // [21824][512] u16     5586944 fl
  float* S0    = ws + 7210240;           // shared region        4587520 fl
  // conv phase:
  u16*   Awv  = (u16*)S0;                  // 3538944 u16 = 1769472 fl
  u16*   Awk  = (u16*)(S0 + 1769472);      //  884736 u16 = 442368 fl
  u16*   Xr   = (u16*)(S0 + 2211840);      // [30][256][512] u16 = 1966080 fl
  float* vt   = S0 + 4177920;              // [10][128][256] f32 = 327680 fl
  u16*   zrow = (u16*)(S0 + 4505600);      // 512 u16 = 256 fl
  // post phases:
  float* aggn    = S0;                     // [100][128][256] = 3276800 fl
  u16*   fsT     = (u16*)(S0 + 3276800);   // [20][256][512] u16 = 1310720 fl
  float* g16_all = S0;                     // [20][256][256] = 1310720 fl (aggn dead)

  // Phase 1: preps + MFMA convs
  k_prep_f<<<384, 256, 0, stream>>>(
      feat[0], feat[1], feat[2], feat[3], feat[4], att, Xf, Xr);
  k_prep_w<<<1080, 256, 0, stream>>>(vqw, vtw, kqw, ktw, Awv, Awk);
  k_prep_cwg<<<384, 256, 0, stream>>>(cw, gamma, cwA, cw2A);
  k_cb<<<5, 256, 0, stream>>>(cw, cbias, beta, cb);
  k_prep_xr<<<320, 256, 0, stream>>>(Xf, Xr, zrow);
  k_conv_mfma<<<600, 256, 0, stream>>>(
      Xr, Awv, Awk, zrow, kqall, vt, f16v, vqb, vtb, kqb, ktb);
  k_prep_vt<<<320, 256, 0, stream>>>(vt, vt2);

  // Phase 2: fused p-chain (all levels, 2 classes per block)
  k_mega<<<800, 256, 0, stream>>>(kqall, vt2, out, aggn);
  k_fuse_fs<<<320, 256, 0, stream>>>(f16v, aggn, fsT);

  // Phase 3: combine
  k_g16_mfma<<<1280, 256, 0, stream>>>(cw2A, fsT, g16_all);
  k_out_final<<<5456, 256, 0, stream>>>(cwA, Xf, g16_all, cb, out);
}

// Round 10
// 363.793 us; speedup vs baseline: 1.6257x; 1.1090x over previous
//
#include <hip/hip_runtime.h>

// Problem constants
constexpr int CIN   = 256;   // feature channels
constexpr int KD    = 32;    // key dim
constexpr int VD    = 128;   // value dim
constexpr int NCLS  = 10;
constexpr int BS    = 4;
constexpr int HW    = 256;   // 16*16
constexpr float BNC = 0.9999950000374997f; // 1/sqrt(1+1e-5)

typedef unsigned short u16;
typedef __attribute__((ext_vector_type(8))) __bf16 bf8v;
typedef __attribute__((ext_vector_type(4))) float f4v;

static __device__ __forceinline__ int imin(int a, int b) { return a < b ? a : b; }

static __device__ __forceinline__ u16 f2bf(float v) {
  union { float f; unsigned u; } x; x.f = v;
  unsigned r = x.u + 0x7FFFu + ((x.u >> 16) & 1u);
  return (u16)(r >> 16);
}
static __device__ __forceinline__ float bf2f(u16 h) {
  union { unsigned u; float f; } x; x.u = ((unsigned)h) << 16;
  return x.f;
}

static __device__ __forceinline__ f4v mfma16(bf8v a, bf8v b, f4v c) {
  return __builtin_amdgcn_mfma_f32_16x16x32_bf16(a, b, c, 0, 0, 0);
}

__constant__ const int c_jbase[5] = {0, 16384, 20480, 21504, 21760};

// ---------------------------------------------------------------------------
// Merged independent preps. Block ranges:
//  [0,384):    feats/att transpose -> Xf (levels) / Xr[20+] (templates)
//  [384,1464): conv weights -> Awv/Awk fragment order
//  [1464,1848): cwA + gamma-folded cw2A
//  [1848,1853): cb
__global__ __launch_bounds__(256) void k_prep1(
    const float* __restrict__ f0, const float* __restrict__ f1,
    const float* __restrict__ f2, const float* __restrict__ f3,
    const float* __restrict__ f4, const float* __restrict__ att,
    const float* __restrict__ vqw, const float* __restrict__ vtw,
    const float* __restrict__ kqw, const float* __restrict__ ktw,
    const float* __restrict__ cw, const float* __restrict__ gamma,
    const float* __restrict__ cbias, const float* __restrict__ beta,
    u16* __restrict__ Xf, u16* __restrict__ Xr,
    u16* __restrict__ Awv, u16* __restrict__ Awk,
    u16* __restrict__ cwA, u16* __restrict__ cw2A, float* __restrict__ cb) {
  __shared__ float sm[16][65];
  int blk = blockIdx.x;
  int tid = threadIdx.x;
  if (blk < 384) {
    const float* fin; u16* dstbase; int SS, px0;
    if (blk < 344) {
      int l, base, nb;
      if (blk < 256)      { l = 0; base = 0;   nb = 64; }
      else if (blk < 320) { l = 1; base = 256; nb = 16; }
      else if (blk < 336) { l = 2; base = 320; nb = 4; }
      else if (blk < 340) { l = 3; base = 336; nb = 1; }
      else                { l = 4; base = 340; nb = 1; }
      int local = blk - base;
      int b = local / nb, chunk = local % nb;
      int S = 64 >> l; SS = S * S;
      px0 = chunk * 64;
      fin = (l == 0 ? f0 : l == 1 ? f1 : l == 2 ? f2 : l == 3 ? f3 : f4)
            + (size_t)b * CIN * SS;
      dstbase = Xf + (size_t)(c_jbase[l] + b * SS) * 512;
    } else {
      int a = blk - 344;
      int imgA = a >> 2, chunk = a & 3;
      SS = 256; px0 = chunk * 64;
      fin = att + (size_t)imgA * CIN * 256;
      dstbase = Xr + (size_t)(20 + imgA) * 131072;
    }
    int px_r = tid & 63, cr = tid >> 6;
    int px_w = tid >> 2, c4 = (tid & 3) * 4;
    for (int cbk = 0; cbk < 16; ++cbk) {
      __syncthreads();
#pragma unroll
      for (int q = 0; q < 4; ++q) {
        int cl = q * 4 + cr;
        float v = 0.f;
        if (px0 + px_r < SS) v = fin[(size_t)(cbk * 16 + cl) * SS + px0 + px_r];
        sm[cl][px_r] = v;
      }
      __syncthreads();
      if (px0 + px_w < SS) {
        u16 hh[4], ll[4];
#pragma unroll
        for (int e = 0; e < 4; ++e) {
          float v = sm[c4 + e][px_w];
          hh[e] = f2bf(v); ll[e] = f2bf(v - bf2f(hh[e]));
        }
        uint2 wh, wl;
        wh.x = (unsigned)hh[0] | ((unsigned)hh[1] << 16); wh.y = (unsigned)hh[2] | ((unsigned)hh[3] << 16);
        wl.x = (unsigned)ll[0] | ((unsigned)ll[1] << 16); wl.y = (unsigned)ll[2] | ((unsigned)ll[3] << 16);
        u16* dst = dstbase + (size_t)(px0 + px_w) * 512 + cbk * 16 + c4;
        *reinterpret_cast<uint2*>(dst) = wh;
        *reinterpret_cast<uint2*>(dst + 256) = wl;
      }
    }
  } else if (blk < 1464) {
    int gid = (blk - 384) * 256 + tid;
    int lane = gid & 63;
    int grp = gid >> 6;
    const float* src; u16* dst; int kc;
    if (grp < 3456) {
      kc = grp % 72; int ot = (grp / 72) % 8; int sid = grp / (72 * 8);
      src = (sid < 5 ? vqw + (size_t)sid * VD * 2304 : vtw) + (size_t)(ot * 16 + (lane & 15)) * 2304;
      dst = Awv + (size_t)grp * 1024;
    } else {
      int g2 = grp - 3456;
      kc = g2 % 72; int ot = (g2 / 72) % 2; int sid = g2 / 144;
      src = (sid < 5 ? kqw + (size_t)sid * KD * 2304 : ktw) + (size_t)(ot * 16 + (lane & 15)) * 2304;
      dst = Awk + (size_t)g2 * 1024;
    }
    int q0 = (lane >> 4) * 8;
    int t = kc >> 3, c0 = (kc & 7) * 32;
#pragma unroll
    for (int i = 0; i < 8; ++i) {
      int c = c0 + q0 + i;
      float v = src[c * 9 + t];
      u16 h = f2bf(v);
      dst[lane * 8 + i] = h;
      dst[512 + lane * 8 + i] = f2bf(v - bf2f(h));
    }
  } else if (blk < 1848) {
    int blk2 = blk - 1464;
    if (blk2 < 64) {
      int gid = blk2 * 256 + tid;
      int oc = gid >> 6, c0 = (gid & 63) * 4;
      float4 v = *reinterpret_cast<const float4*>(cw + (size_t)oc * 512 + c0);
      const float* vv = (const float*)&v;
      u16 h[4], l[4];
#pragma unroll
      for (int e = 0; e < 4; ++e) { h[e] = f2bf(vv[e]); l[e] = f2bf(vv[e] - bf2f(h[e])); }
      uint2 wh, wl;
      wh.x = (unsigned)h[0] | ((unsigned)h[1] << 16); wh.y = (unsigned)h[2] | ((unsigned)h[3] << 16);
      wl.x = (unsigned)l[0] | ((unsigned)l[1] << 16); wl.y = (unsigned)l[2] | ((unsigned)l[3] << 16);
      *reinterpret_cast<uint2*>(cwA + (size_t)oc * 256 + c0) = wh;
      *reinterpret_cast<uint2*>(cwA + 65536 + (size_t)oc * 256 + c0) = wl;
    } else {
      int gid = (blk2 - 64) * 256 + tid;
      int l = gid / 16384, rem = gid % 16384;
      int oc = rem >> 6, c0 = (rem & 63) * 4;
      u16 h[4], lo[4];
#pragma unroll
      for (int e = 0; e < 4; ++e) {
        int c = c0 + e;
        float v = cw[(size_t)oc * 512 + 256 + c] * (gamma[l * 256 + c] * BNC);
        h[e] = f2bf(v); lo[e] = f2bf(v - bf2f(h[e]));
      }
      uint2 wh, wl;
      wh.x = (unsigned)h[0] | ((unsigned)h[1] << 16); wh.y = (unsigned)h[2] | ((unsigned)h[3] << 16);
      wl.x = (unsigned)lo[0] | ((unsigned)lo[1] << 16); wl.y = (unsigned)lo[2] | ((unsigned)lo[3] << 16);
      *reinterpret_cast<uint2*>(cw2A + (size_t)l * 65536 + oc * 256 + c0) = wh;
      *reinterpret_cast<uint2*>(cw2A + 327680 + (size_t)l * 65536 + oc * 256 + c0) = wl;
    }
  } else {
    int l = blk - 1848, oc = tid;
    float s = cbias[oc];
    for (int c = 0; c < CIN; ++c)
      s += cw[(size_t)oc * 512 + 256 + c] * beta[l * CIN + c];
    cb[l * CIN + oc] = s;
  }
}

// ---------------------------------------------------------------------------
// Level imgs: bilinear-resize Xf rows -> Xr[img][px][2][256]. grid = 320.
// Also zeroes zrow (block 0).
__global__ __launch_bounds__(256) void k_prep_xr(
    const u16* __restrict__ Xf, u16* __restrict__ Xr, u16* __restrict__ zrow) {
  int blk = blockIdx.x;
  int img = blk >> 4, yr = blk & 15;
  int l = img >> 2, b = img & 3;
  int S = 64 >> l, SS = S * S;
  int c = threadIdx.x;
  if (blk == 0) { zrow[c] = 0; zrow[256 + c] = 0; }
  float cyf = (float)(yr * (S - 1)) / 15.0f;
  int ylo = imin((int)cyf, S - 2); float fy = cyf - (float)ylo;
  u16* dst = Xr + ((size_t)img * 256 + yr * 16) * 512;
  const u16* srcb = Xf + (size_t)(c_jbase[l] + b * SS) * 512;
  for (int x = 0; x < 16; ++x) {
    float cxf = (float)(x * (S - 1)) / 15.0f;
    int xlo = imin((int)cxf, S - 2); float fx = cxf - (float)xlo;
    const u16* r00 = srcb + (size_t)(ylo * S + xlo) * 512;
    const u16* r10 = srcb + (size_t)((ylo + 1) * S + xlo) * 512;
    float v00 = bf2f(r00[c]) + bf2f(r00[256 + c]);
    float v01 = bf2f(r00[512 + c]) + bf2f(r00[768 + c]);
    float v10 = bf2f(r10[c]) + bf2f(r10[256 + c]);
    float v11 = bf2f(r10[512 + c]) + bf2f(r10[768 + c]);
    float v = (1.f - fy) * ((1.f - fx) * v00 + fx * v01)
            + fy * ((1.f - fx) * v10 + fx * v11);
    u16 h = f2bf(v);
    dst[x * 512 + c] = h;
    dst[x * 512 + 256 + c] = f2bf(v - bf2f(h));
  }
}

// ---------------------------------------------------------------------------
// MFMA conv from Xr (16x16 transposed split-bf16, zero-row for padding).
// grid = 600. V-template output goes straight to split-bf16 vt2.
__global__ __launch_bounds__(256) void k_conv_mfma(
    const u16* __restrict__ Xr, const u16* __restrict__ Awv, const u16* __restrict__ Awk,
    const u16* __restrict__ zrow,
    float* __restrict__ kqall, u16* __restrict__ vt2, float* __restrict__ f16v,
    const float* __restrict__ vqb, const float* __restrict__ vtb,
    const float* __restrict__ kqb, const float* __restrict__ ktb) {
  int wid = blockIdx.x * 4 + (threadIdx.x >> 6);
  int lane = threadIdx.x & 63;
  bool isV = wid < 1920;
  int img, ot, yp;
  if (isV) { img = wid >> 6; int r = wid & 63; ot = r >> 3; yp = r & 7; }
  else     { int j = wid - 1920; img = j >> 4; int r = j & 15; ot = r >> 3; yp = r & 7; }
  int wset = img < 20 ? (img >> 2) : 5;

  const u16* Ab = isV ? Awv + ((size_t)(wset * 8 + ot)) * 72 * 1024
                      : Awk + ((size_t)(wset * 2 + ot)) * 72 * 1024;
  const u16* Xb = Xr + (size_t)img * 131072;
  int xcol = lane & 15, kg = lane >> 4;
  int y0 = yp * 2, y1 = y0 + 1;

  f4v acc0 = {0.f, 0.f, 0.f, 0.f}, acc1 = {0.f, 0.f, 0.f, 0.f};
  for (int t = 0; t < 9; ++t) {
    int dy = (t >= 6) ? 2 : (t >= 3 ? 1 : 0);
    int dx = t - dy * 3;
    int yy0 = y0 + dy - 1, yy1 = yy0 + 1;
    int xx = xcol + dx - 1;
    bool xok = (unsigned)xx < 16u;
    const u16* base0 = (xok && (unsigned)yy0 < 16u)
                       ? Xb + (size_t)(yy0 * 16 + xx) * 512 : zrow;
    const u16* base1 = (xok && (unsigned)yy1 < 16u)
                       ? Xb + (size_t)(yy1 * 16 + xx) * 512 : zrow;
    const u16* Xr0 = base0 + kg * 8;
    const u16* Xr1 = base1 + kg * 8;
    const u16* Ak = Ab + (size_t)t * 8 * 1024 + lane * 8;
#pragma unroll
    for (int cc = 0; cc < 8; ++cc) {
      bf8v ah = *reinterpret_cast<const bf8v*>(Ak + cc * 1024);
      bf8v al = *reinterpret_cast<const bf8v*>(Ak + cc * 1024 + 512);
      bf8v bh0 = *reinterpret_cast<const bf8v*>(Xr0 + cc * 32);
      bf8v bl0 = *reinterpret_cast<const bf8v*>(Xr0 + cc * 32 + 256);
      bf8v bh1 = *reinterpret_cast<const bf8v*>(Xr1 + cc * 32);
      bf8v bl1 = *reinterpret_cast<const bf8v*>(Xr1 + cc * 32 + 256);
      acc0 = mfma16(ah, bh0, acc0);
      acc0 = mfma16(ah, bl0, acc0);
      acc0 = mfma16(al, bh0, acc0);
      acc1 = mfma16(ah, bh1, acc1);
      acc1 = mfma16(ah, bl1, acc1);
      acc1 = mfma16(al, bh1, acc1);
    }
  }

  int ocbase = ot * 16;
  if (isV && img >= 20) {
    // template V -> vt2 split bf16 directly
    int n = img - 20;
    u16* d2 = vt2 + ((size_t)n * VD + ocbase) * HW;
#pragma unroll
    for (int i = 0; i < 4; ++i) {
      int ocl = kg * 4 + i;
      float bv = vtb[ocbase + ocl];
      float va = acc0[i] + bv, vb = acc1[i] + bv;
      u16 ha = f2bf(va), hb = f2bf(vb);
      size_t ia = (size_t)ocl * HW + y0 * 16 + xcol;
      size_t ib = (size_t)ocl * HW + y1 * 16 + xcol;
      d2[ia] = ha; d2[ia + 327680] = f2bf(va - bf2f(ha));
      d2[ib] = hb; d2[ib + 327680] = f2bf(vb - bf2f(hb));
    }
    return;
  }
  float scale = 1.f;
  const float* bias;
  float* dst;
  if (isV) { dst = f16v + ((size_t)img * VD + ocbase) * HW; bias = vqb + wset * VD + ocbase; scale = (float)NCLS; }
  else if (img < 20) { dst = kqall + ((size_t)img * KD + ocbase) * HW; bias = kqb + wset * KD + ocbase; }
  else { dst = kqall + (size_t)20 * KD * HW + ((size_t)(img - 20) * KD + ocbase) * HW; bias = ktb + ocbase; }
#pragma unroll
  for (int i = 0; i < 4; ++i) {
    int ocl = kg * 4 + i;
    float bv = bias[ocl];
    dst[(size_t)ocl * HW + y0 * 16 + xcol] = (acc0[i] + bv) * scale;
    dst[(size_t)ocl * HW + y1 * 16 + xcol] = (acc1[i] + bv) * scale;
  }
}

// ---------------------------------------------------------------------------
// MEGA: block = (l, bn, jt of 32 j): QK^T -> softmax -> p in LDS ->
// fa direct to out -> aggn MFMA. grid = 1600 x 256. One class per block.
__global__ __launch_bounds__(256) void k_mega(
    const float* __restrict__ kqall, const u16* __restrict__ vt2,
    float* __restrict__ out, float* __restrict__ aggn) {
  int blk = blockIdx.x;
  int l = blk / 320;
  int r = blk % 320;
  int bn = r >> 3, jt = r & 7;
  int b = bn / NCLS, n = bn % NCLS;
  int t = threadIdx.x;
  int iq = t >> 5, jl = t & 31;
  int j = jt * 32 + jl;

  __shared__ float buf[8224];   // kq [32][256] staging, then p [32 j][257]
  __shared__ float red[512];

  const float* ktb = kqall + 20 * KD * HW;
  float ktr[KD];
#pragma unroll
  for (int k = 0; k < KD; ++k) ktr[k] = ktb[((size_t)n * KD + k) * HW + j];
  const float* kqb = kqall + (size_t)(l * 4 + b) * KD * HW;
  for (int s = t; s < KD * HW; s += 256) buf[s] = kqb[s];
  __syncthreads();

  float v[32];
#pragma unroll
  for (int ii = 0; ii < 32; ++ii) v[ii] = 0.f;
  for (int k = 0; k < KD; ++k) {
    float a = ktr[k];
    const float4* q4 = (const float4*)&buf[k * 256 + iq * 32];
#pragma unroll
    for (int q = 0; q < 8; ++q) {
      float4 u = q4[q];
      v[q * 4 + 0] += u.x * a; v[q * 4 + 1] += u.y * a;
      v[q * 4 + 2] += u.z * a; v[q * 4 + 3] += u.w * a;
    }
  }
  float ml = -1e30f;
#pragma unroll
  for (int ii = 0; ii < 32; ++ii) ml = fmaxf(ml, v[ii]);
  float sl = 0.f;
#pragma unroll
  for (int ii = 0; ii < 32; ++ii) sl += __expf(v[ii] - ml);
  red[t] = ml;
  red[256 + t] = sl;
  __syncthreads();          // all buf(kq) reads done too
  float M = -1e30f;
#pragma unroll
  for (int q = 0; q < 8; ++q) M = fmaxf(M, red[q * 32 + jl]);
  float Ssum = 0.f;
#pragma unroll
  for (int q = 0; q < 8; ++q) Ssum += red[256 + q * 32 + jl] * __expf(red[q * 32 + jl] - M);
  float inv = 1.0f / Ssum;
#pragma unroll
  for (int ii = 0; ii < 32; ++ii)
    buf[jl * 257 + iq * 32 + ii] = __expf(v[ii] - M) * inv;
  __syncthreads();

  // ---- fa: bilinear over i-grid, direct to out ----
  int S_ = 64 >> l, shift = 6 - l, SS = S_ * S_;
  const size_t fa_off[5] = {5586944, 47529984, 58015744, 60637184, 61292544};
  float* ob = out + fa_off[l] + ((size_t)bn * HW + jt * 32) * SS;
  int tot = SS << 5;
  for (int base = t * 4; base < tot; base += 1024) {
    int jj = base >> (2 * shift);
    int rest = base & (SS - 1);
    int X0 = rest & (S_ - 1), Y = rest >> shift;
    float cyf = (float)(Y * 15) / (float)(S_ - 1);
    int ylo = imin((int)cyf, 14); float fy = cyf - (float)ylo;
    const float* prow = &buf[jj * 257];
    float4 rv; float* rr = (float*)&rv;
#pragma unroll
    for (int t4 = 0; t4 < 4; ++t4) {
      int X = X0 + t4;
      float cxf = (float)(X * 15) / (float)(S_ - 1);
      int xlo = imin((int)cxf, 14); float fx = cxf - (float)xlo;
      int i00 = ylo * 16 + xlo;
      float v0 = prow[i00],      v1 = prow[i00 + 1];
      float v2 = prow[i00 + 16], v3 = prow[i00 + 17];
      rr[t4] = (1.f - fy) * ((1.f - fx) * v0 + fx * v1)
             + fy * ((1.f - fx) * v2 + fx * v3);
    }
    *(float4*)(ob + (size_t)jj * SS + rest) = rv;
  }

  // ---- aggn: [128 c][32 j] via MFMA; wave w owns c-tiles {2w, 2w+1} ----
  int w = t >> 6, lane = t & 63;
  int row = lane & 15, kg = lane >> 4;
  f4v acc[2][2] = {{{0.f,0.f,0.f,0.f},{0.f,0.f,0.f,0.f}},
                   {{0.f,0.f,0.f,0.f},{0.f,0.f,0.f,0.f}}};
  for (int kc = 0; kc < 8; ++kc) {
    bf8v ah[2], al[2];
#pragma unroll
    for (int ctl = 0; ctl < 2; ++ctl) {
      int ct = w * 2 + ctl;
      const u16* vh = vt2 + ((size_t)n * VD + ct * 16 + row) * 256 + kc * 32 + kg * 8;
      ah[ctl] = *reinterpret_cast<const bf8v*>(vh);
      al[ctl] = *reinterpret_cast<const bf8v*>(vh + 327680);
    }
#pragma unroll
    for (int jt2 = 0; jt2 < 2; ++jt2) {
      union { u16 u[8]; bf8v v8; } Bh, Bl;
#pragma unroll
      for (int e = 0; e < 8; ++e) {
        float f = buf[(jt2 * 16 + row) * 257 + kc * 32 + kg * 8 + e];
        u16 h = f2bf(f);
        Bh.u[e] = h; Bl.u[e] = f2bf(f - bf2f(h));
      }
#pragma unroll
      for (int ctl = 0; ctl < 2; ++ctl) {
        acc[ctl][jt2] = mfma16(ah[ctl], Bh.v8, acc[ctl][jt2]);
        acc[ctl][jt2] = mfma16(ah[ctl], Bl.v8, acc[ctl][jt2]);
        acc[ctl][jt2] = mfma16(al[ctl], Bh.v8, acc[ctl][jt2]);
      }
    }
  }
  float* ab = aggn + (size_t)(l * 40 + bn) * VD * HW;
#pragma unroll
  for (int ctl = 0; ctl < 2; ++ctl)
#pragma unroll
    for (int jt2 = 0; jt2 < 2; ++jt2)
#pragma unroll
      for (int i = 0; i < 4; ++i)
        ab[(size_t)(w * 32 + ctl * 16 + kg * 4 + i) * HW + jt * 32 + jt2 * 16 + row]
            = acc[ctl][jt2][i];
}

// ---------------------------------------------------------------------------
// Fuse: fsT[img][j][2][256c] (split bf16) from f16v (c<128, vq*10) and
// n-summed aggn (c>=128). grid = 320 (img, jc of 16).
__global__ __launch_bounds__(256) void k_fuse_fs(
    const float* __restrict__ f16v, const float* __restrict__ aggn,
    u16* __restrict__ fsT) {
  int blk = blockIdx.x;
  int img = blk >> 4, jc = blk & 15;
  int j0 = jc * 16;
  int l = img >> 2, b = img & 3;
  int tid = threadIdx.x;
  __shared__ float fs[256][17];
  for (int pass = 0; pass < 16; ++pass) {
    int cc = pass * 16 + (tid >> 4);
    int jj = tid & 15;
    float v;
    if (cc < 128) {
      v = f16v[((size_t)img * VD + cc) * HW + j0 + jj];
    } else {
      const float* ab = aggn + ((size_t)(l * 40 + b * 10) * VD + cc - 128) * HW + j0 + jj;
      v = 0.f;
#pragma unroll
      for (int n = 0; n < NCLS; ++n) v += ab[(size_t)n * VD * HW];
    }
    fs[cc][jj] = v;
  }
  __syncthreads();
  int j = tid >> 4, cg = (tid & 15) * 16;
  u16* dst = fsT + ((size_t)img * 256 + j0 + j) * 512 + cg;
#pragma unroll
  for (int e = 0; e < 16; ++e) {
    float v = fs[cg + e][j];
    u16 h = f2bf(v);
    dst[e] = h;
    dst[256 + e] = f2bf(v - bf2f(h));
  }
}

// ---------------------------------------------------------------------------
// g16 via MFMA: g16[img][oc][j] = sum_c cw2_l[oc][c] * fs[img][c][j].
// wave = (img, octile, jt). grid = 1280.
__global__ __launch_bounds__(256) void k_g16_mfma(
    const u16* __restrict__ cw2A, const u16* __restrict__ fsT,
    float* __restrict__ g16_all) {
  int wid = blockIdx.x * 4 + (threadIdx.x >> 6);   // 0..5119
  int lane = threadIdx.x & 63;
  int img = wid >> 8;
  int r = wid & 255;
  int octile = r >> 4, jt = r & 15;
  int l = img >> 2;
  int row = lane & 15, kg = lane >> 4;
  const u16* Ah = cw2A + (size_t)l * 65536 + (octile * 16 + row) * 256 + kg * 8;
  const u16* Al = Ah + 327680;
  const u16* Bh = fsT + ((size_t)img * 256 + jt * 16 + row) * 512 + kg * 8;
  const u16* Bl = Bh + 256;
  f4v acc = {0.f, 0.f, 0.f, 0.f};
#pragma unroll
  for (int kc = 0; kc < 8; ++kc) {
    bf8v ah = *reinterpret_cast<const bf8v*>(Ah + kc * 32);
    bf8v al = *reinterpret_cast<const bf8v*>(Al + kc * 32);
    bf8v bh = *reinterpret_cast<const bf8v*>(Bh + kc * 32);
    bf8v bl = *reinterpret_cast<const bf8v*>(Bl + kc * 32);
    acc = mfma16(ah, bh, acc);
    acc = mfma16(ah, bl, acc);
    acc = mfma16(al, bh, acc);
  }
#pragma unroll
  for (int i = 0; i < 4; ++i)
    g16_all[((size_t)img * CIN + octile * 16 + kg * 4 + i) * HW + jt * 16 + row] = acc[i];
}

// ---------------------------------------------------------------------------
// Final: out = cw[:, :256].f (MFMA) + bilinear(g16) + cb. grid = 5456.
__global__ __launch_bounds__(256) void k_out_final(
    const u16* __restrict__ cwA, const u16* __restrict__ Xf,
    const float* __restrict__ g16_all, const float* __restrict__ cb_all,
    float* __restrict__ out) {
  int wid = blockIdx.x * 4 + (threadIdx.x >> 6);
  int lane = threadIdx.x & 63;
  int pt = wid >> 4, octile = wid & 15;
  int l, lb, tl;
  if (pt < 1024)      { l = 0; lb = 0;    tl = 256; }
  else if (pt < 1280) { l = 1; lb = 1024; tl = 64; }
  else if (pt < 1344) { l = 2; lb = 1280; tl = 16; }
  else if (pt < 1360) { l = 3; lb = 1344; tl = 4; }
  else                { l = 4; lb = 1360; tl = 1; }
  int rem = pt - lb;
  int b = rem / tl;
  int pxin = (rem % tl) * 16;
  const size_t ooff[5] = {0, 4194304, 5242880, 5505024, 5570560};
  int S = 64 >> l, SS = S * S, shift = 6 - l;
  int row = lane & 15, kg = lane >> 4;
  int gpx = c_jbase[l] + b * SS + pxin + row;

  const u16* Ah = cwA + ((size_t)(octile * 16 + row)) * 256 + kg * 8;
  const u16* Al = Ah + 65536;
  const u16* Bh = Xf + (size_t)gpx * 512 + kg * 8;
  const u16* Bl = Bh + 256;
  f4v acc = {0.f, 0.f, 0.f, 0.f};
#pragma unroll
  for (int kc = 0; kc < 8; ++kc) {
    bf8v ah = *reinterpret_cast<const bf8v*>(Ah + kc * 32);
    bf8v al = *reinterpret_cast<const bf8v*>(Al + kc * 32);
    bf8v bh = *reinterpret_cast<const bf8v*>(Bh + kc * 32);
    bf8v bl = *reinterpret_cast<const bf8v*>(Bl + kc * 32);
    acc = mfma16(ah, bh, acc);
    acc = mfma16(ah, bl, acc);
    acc = mfma16(al, bh, acc);
  }

  int px = pxin + row;
  int Xc = px & (S - 1), Y = px >> shift;
  float cyf = (float)(Y * 15) / (float)(S - 1);
  int ylo = imin((int)cyf, 14); float fy = cyf - (float)ylo;
  float cxf = (float)(Xc * 15) / (float)(S - 1);
  int xlo = imin((int)cxf, 14); float fx = cxf - (float)xlo;
  int i00 = ylo * 16 + xlo;
  const float* gbase = g16_all + ((size_t)(l * 4 + b) * CIN + octile * 16 + kg * 4) * HW;
  float* ob = out + ooff[l] + ((size_t)b * CIN + octile * 16) * SS + px;
#pragma unroll
  for (int i = 0; i < 4; ++i) {
    const float* g = gbase + (size_t)i * HW + i00;
    float v0 = g[0], v1 = g[1], v2 = g[16], v3 = g[17];
    float bil = (1.f - fy) * ((1.f - fx) * v0 + fx * v1)
              + fy * ((1.f - fx) * v2 + fx * v3);
    ob[(size_t)(kg * 4 + i) * SS] = acc[i] + bil + cb_all[l * CIN + octile * 16 + kg * 4 + i];
  }
}

// ===========================================================================
extern "C" void kernel_launch(void* const* d_in, const int* in_sizes, int n_in,
                              void* d_out, int out_size, void* d_ws, size_t ws_size,
                              hipStream_t stream) {
  const float* feat[5];
  for (int l = 0; l < 5; ++l) feat[l] = (const float*)d_in[l];
  const float* att   = (const float*)d_in[5];
  const float* ktw   = (const float*)d_in[6];
  const float* ktb   = (const float*)d_in[7];
  const float* vtw   = (const float*)d_in[8];
  const float* vtb   = (const float*)d_in[9];
  const float* kqw   = (const float*)d_in[10];
  const float* kqb   = (const float*)d_in[11];
  const float* vqw   = (const float*)d_in[12];
  const float* vqb   = (const float*)d_in[13];
  const float* gamma = (const float*)d_in[14];
  const float* beta  = (const float*)d_in[15];
  const float* cw    = (const float*)d_in[16];
  const float* cbias = (const float*)d_in[17];
  float* out = (float*)d_out;

  // workspace layout (floats), total 15,074,560 fl = 60.3 MB (ws ~1 GB)
  float* ws    = (float*)d_ws;
  float* kqall = ws;                     // [30][32][256]        245760
  float* f16v  = ws + 245760;            // [20][128][256]       655360 (vq*10)
  u16*   vt2   = (u16*)(ws + 901120);    // [2][10][128][256]u16 327680 fl
  u16*   cwA   = (u16*)(ws + 1228800);   // [2][256][256] u16    65536 fl
  u16*   cw2A  = (u16*)(ws + 1294336);   // [2][5][256][256]u16  327680 fl
  float* cb    = ws + 1622016;           // [5][256]             1280
  u16*   Xf    = (u16*)(ws + 1623296);   // [21824][512] u16     5586944 fl
  float* S0    = ws + 7210240;           // shared region        7864320 fl
  // conv phase:
  u16*   Awv  = (u16*)S0;                  // 3538944 u16 = 1769472 fl
  u16*   Awk  = (u16*)(S0 + 1769472);      //  884736 u16 = 442368 fl
  u16*   Xr   = (u16*)(S0 + 2211840);      // [30][256][512] u16 = 1966080 fl
  u16*   zrow = (u16*)(S0 + 4177920);      // 512 u16 = 256 fl
  // post phases:
  float* aggn    = S0;                     // [200][128][256] = 6553600 fl
  u16*   fsT     = (u16*)(S0 + 6553600);   // [20][256][512] u16 = 1310720 fl
  float* g16_all = S0;                     // [20][256][256] = 1310720 fl (aggn dead)

  // Phase 1: merged preps, then resize + conv
  k_prep1<<<1853, 256, 0, stream>>>(
      feat[0], feat[1], feat[2], feat[3], feat[4], att,
      vqw, vtw, kqw, ktw, cw, gamma, cbias, beta,
      Xf, Xr, Awv, Awk, cwA, cw2A, cb);
  k_prep_xr<<<320, 256, 0, stream>>>(Xf, Xr, zrow);
  k_conv_mfma<<<600, 256, 0, stream>>>(
      Xr, Awv, Awk, zrow, kqall, vt2, f16v, vqb, vtb, kqb, ktb);

  // Phase 2: fused p-chain (all levels, one class per block)
  k_mega<<<1600, 256, 0, stream>>>(kqall, vt2, out, aggn);
  k_fuse_fs<<<320, 256, 0, stream>>>(f16v, aggn, fsT);

  // Phase 3: combine
  k_g16_mfma<<<1280, 256, 0, stream>>>(cw2A, fsT, g16_all);
  k_out_final<<<5456, 256, 0, stream>>>(cwA, Xf, g16_all, cb, out);
}